// Round 1
// baseline (513.605 us; speedup 1.0000x reference)
//
#include <hip/hip_runtime.h>

// Problem constants (B,L,D,H fixed from reference)
#define Bsz  8
#define Lsz  1024
#define Dsz  1024
#define Hh   16
#define HDsz 64
#define NSsz 8
#define LSsz 1016

typedef short  bf16x8 __attribute__((ext_vector_type(8)));   // 8 bf16 (4 VGPRs)
typedef float  f32x4  __attribute__((ext_vector_type(4)));

#define GLB(p) ((const __attribute__((address_space(1))) unsigned int*)(p))
#define LDSP(p) ((__attribute__((address_space(3))) unsigned int*)(p))

__device__ __forceinline__ float bf2f(unsigned short u) {
    union { unsigned int i; float f; } v; v.i = ((unsigned int)u) << 16; return v.f;
}
__device__ __forceinline__ unsigned short f2bf(float f) {
    union { float f; unsigned int i; } v; v.f = f;
    unsigned int x = v.i;
    return (unsigned short)((x + 0x7FFFu + ((x >> 16) & 1u)) >> 16);
}

// ---------------------------------------------------------------------------
// Cast kernel: x (fp32) -> xb (bf16); Wq_s|Wk_s|Wv_s -> Wcat; W_out -> Wob.
// Pure bandwidth; float4 loads, ushort4 stores.
// ---------------------------------------------------------------------------
__global__ __launch_bounds__(256) void cast_kernel(
    const float* __restrict__ x,
    const float* __restrict__ wq, const float* __restrict__ wk,
    const float* __restrict__ wv, const float* __restrict__ wo,
    unsigned short* __restrict__ xb,
    unsigned short* __restrict__ wcat,
    unsigned short* __restrict__ wob)
{
    const size_t NX = 2097152;   // float4s in x (8388608 elems)
    const size_t NW = 262144;    // float4s per DxD weight
    size_t i = (size_t)blockIdx.x * 256 + threadIdx.x;
    const size_t stride = (size_t)gridDim.x * 256;
    const size_t total = NX + 4 * NW;
    for (; i < total; i += stride) {
        const float* src; unsigned short* dst; size_t off;
        if (i < NX)               { src = x;  dst = xb;             off = i; }
        else if (i < NX + NW)     { src = wq; dst = wcat;           off = i - NX; }
        else if (i < NX + 2 * NW) { src = wk; dst = wcat + 1048576; off = i - NX - NW; }
        else if (i < NX + 3 * NW) { src = wv; dst = wcat + 2097152; off = i - NX - 2 * NW; }
        else                      { src = wo; dst = wob;            off = i - NX - 3 * NW; }
        float4 v = reinterpret_cast<const float4*>(src)[off];
        ushort4 o;
        o.x = f2bf(v.x); o.y = f2bf(v.y); o.z = f2bf(v.z); o.w = f2bf(v.w);
        reinterpret_cast<ushort4*>(dst)[off] = o;
    }
}

// ---------------------------------------------------------------------------
// Fused QKV GEMM (m97-style): [8192 x 3072] = xb[8192x1024] @ Wcat[3072x1024]^T
// 128x128 tile, BK=64, global_load_lds width=16 staging, bf16 MFMA 16x16x32.
// ---------------------------------------------------------------------------
__global__ __launch_bounds__(256) void gemm_qkv_kernel(
    const unsigned short* __restrict__ Ab,
    const unsigned short* __restrict__ Wb,
    unsigned short* __restrict__ Qo,
    unsigned short* __restrict__ Ko,
    unsigned short* __restrict__ Vo)
{
    __shared__ __align__(16) unsigned short As[128 * 64];  // 16 KB
    __shared__ __align__(16) unsigned short Bs[128 * 64];  // 16 KB

    const int tid  = threadIdx.x;
    const int lane = tid & 63;
    const int wave = tid >> 6;
    const int wm   = wave >> 1;
    const int wn   = wave & 1;
    const int lr   = lane & 15;
    const int lq   = lane >> 4;
    const int m0   = blockIdx.y * 128;
    const int n0   = blockIdx.x * 128;

    const int lrow = lane >> 3;          // 0..7
    const int lcol = (lane & 7) << 3;    // 0..56

    f32x4 acc[4][4];
    #pragma unroll
    for (int i = 0; i < 4; ++i)
        #pragma unroll
        for (int j = 0; j < 4; ++j)
            acc[i][j] = (f32x4){0.f, 0.f, 0.f, 0.f};

    for (int k0 = 0; k0 < 1024; k0 += 64) {
        #pragma unroll
        for (int it = 0; it < 4; ++it) {
            int row = it * 32 + wave * 8 + lrow;
            const unsigned short* ga = &Ab[(size_t)(m0 + row) * 1024 + k0 + lcol];
            const unsigned short* gb = &Wb[(size_t)(n0 + row) * 1024 + k0 + lcol];
            __builtin_amdgcn_global_load_lds(GLB(ga), LDSP(&As[it * 2048 + wave * 512]), 16, 0, 0);
            __builtin_amdgcn_global_load_lds(GLB(gb), LDSP(&Bs[it * 2048 + wave * 512]), 16, 0, 0);
        }
        __syncthreads();

        #pragma unroll
        for (int ks = 0; ks < 2; ++ks) {
            bf16x8 af[4], bfr[4];
            #pragma unroll
            for (int i = 0; i < 4; ++i)
                af[i] = *reinterpret_cast<const bf16x8*>(
                    &As[(wm * 64 + i * 16 + lr) * 64 + ks * 32 + lq * 8]);
            #pragma unroll
            for (int j = 0; j < 4; ++j)
                bfr[j] = *reinterpret_cast<const bf16x8*>(
                    &Bs[(wn * 64 + j * 16 + lr) * 64 + ks * 32 + lq * 8]);
            #pragma unroll
            for (int i = 0; i < 4; ++i)
                #pragma unroll
                for (int j = 0; j < 4; ++j)
                    acc[i][j] = __builtin_amdgcn_mfma_f32_16x16x32_bf16(
                        af[i], bfr[j], acc[i][j], 0, 0, 0);
        }
        __syncthreads();
    }

    const int t  = n0 >> 10;                 // uniform per block
    const int d0 = n0 & 1023;
    unsigned short* Out = (t == 0 ? Qo : t == 1 ? Ko : Vo);
    #pragma unroll
    for (int i = 0; i < 4; ++i) {
        #pragma unroll
        for (int j = 0; j < 4; ++j) {
            int col = d0 + wn * 64 + j * 16 + lr;
            #pragma unroll
            for (int r = 0; r < 4; ++r) {
                int row = m0 + wm * 64 + i * 16 + lq * 4 + r;
                Out[(size_t)row * 1024 + col] = f2bf(acc[i][j][r]);
            }
        }
    }
}

// ---------------------------------------------------------------------------
// Final projection GEMM: out[8192x1024] fp32 = Ob[8192x1024] @ Wob[1024x1024]^T
// ---------------------------------------------------------------------------
__global__ __launch_bounds__(256) void gemm_obf_kernel(
    const unsigned short* __restrict__ Ab,
    const unsigned short* __restrict__ Wb,
    float* __restrict__ Co)
{
    __shared__ __align__(16) unsigned short As[128 * 64];
    __shared__ __align__(16) unsigned short Bs[128 * 64];

    const int tid  = threadIdx.x;
    const int lane = tid & 63;
    const int wave = tid >> 6;
    const int wm   = wave >> 1;
    const int wn   = wave & 1;
    const int lr   = lane & 15;
    const int lq   = lane >> 4;
    const int m0   = blockIdx.y * 128;
    const int n0   = blockIdx.x * 128;

    const int lrow = lane >> 3;
    const int lcol = (lane & 7) << 3;

    f32x4 acc[4][4];
    #pragma unroll
    for (int i = 0; i < 4; ++i)
        #pragma unroll
        for (int j = 0; j < 4; ++j)
            acc[i][j] = (f32x4){0.f, 0.f, 0.f, 0.f};

    for (int k0 = 0; k0 < 1024; k0 += 64) {
        #pragma unroll
        for (int it = 0; it < 4; ++it) {
            int row = it * 32 + wave * 8 + lrow;
            const unsigned short* ga = &Ab[(size_t)(m0 + row) * 1024 + k0 + lcol];
            const unsigned short* gb = &Wb[(size_t)(n0 + row) * 1024 + k0 + lcol];
            __builtin_amdgcn_global_load_lds(GLB(ga), LDSP(&As[it * 2048 + wave * 512]), 16, 0, 0);
            __builtin_amdgcn_global_load_lds(GLB(gb), LDSP(&Bs[it * 2048 + wave * 512]), 16, 0, 0);
        }
        __syncthreads();

        #pragma unroll
        for (int ks = 0; ks < 2; ++ks) {
            bf16x8 af[4], bfr[4];
            #pragma unroll
            for (int i = 0; i < 4; ++i)
                af[i] = *reinterpret_cast<const bf16x8*>(
                    &As[(wm * 64 + i * 16 + lr) * 64 + ks * 32 + lq * 8]);
            #pragma unroll
            for (int j = 0; j < 4; ++j)
                bfr[j] = *reinterpret_cast<const bf16x8*>(
                    &Bs[(wn * 64 + j * 16 + lr) * 64 + ks * 32 + lq * 8]);
            #pragma unroll
            for (int i = 0; i < 4; ++i)
                #pragma unroll
                for (int j = 0; j < 4; ++j)
                    acc[i][j] = __builtin_amdgcn_mfma_f32_16x16x32_bf16(
                        af[i], bfr[j], acc[i][j], 0, 0, 0);
        }
        __syncthreads();
    }

    #pragma unroll
    for (int i = 0; i < 4; ++i) {
        #pragma unroll
        for (int j = 0; j < 4; ++j) {
            int col = n0 + wn * 64 + j * 16 + lr;
            #pragma unroll
            for (int r = 0; r < 4; ++r) {
                int row = m0 + wm * 64 + i * 16 + lq * 4 + r;
                Co[(size_t)row * 1024 + col] = acc[i][j][r];
            }
        }
    }
}

// ---------------------------------------------------------------------------
// Fallback GEMM (round-5 structure): C = A @ W^T, fp32 W staged via VGPRs.
// ---------------------------------------------------------------------------
#define GBM 128
#define GBN 128
#define GBK 64

template <bool A_F32, bool C_F32>
__global__ __launch_bounds__(256) void gemm_bt_kernel(
    const void* __restrict__ Av,
    const float* __restrict__ W,
    void* __restrict__ Cv,
    int M, int N, int K)
{
    __shared__ unsigned short As[GBM][GBK];
    __shared__ unsigned short Ws[GBN][GBK];

    const int tid  = threadIdx.x;
    const int lane = tid & 63;
    const int wave = tid >> 6;
    const int wm   = wave >> 1;
    const int wn   = wave & 1;
    const int lr   = lane & 15;
    const int lq   = lane >> 4;
    const int m0   = blockIdx.y * GBM;
    const int n0   = blockIdx.x * GBN;

    f32x4 acc[4][4];
    #pragma unroll
    for (int i = 0; i < 4; ++i)
        #pragma unroll
        for (int j = 0; j < 4; ++j)
            acc[i][j] = (f32x4){0.f, 0.f, 0.f, 0.f};

    for (int k0 = 0; k0 < K; k0 += GBK) {
        if (A_F32) {
            const float* A = (const float*)Av;
            #pragma unroll
            for (int i = 0; i < 8; ++i) {
                int idx = tid + i * 256;
                int row = idx >> 4;
                int c4  = idx & 15;
                float4 a = *reinterpret_cast<const float4*>(
                    &A[(size_t)(m0 + row) * K + k0 + c4 * 4]);
                ushort4 o;
                o.x = f2bf(a.x); o.y = f2bf(a.y);
                o.z = f2bf(a.z); o.w = f2bf(a.w);
                *reinterpret_cast<ushort4*>(&As[row][c4 * 4]) = o;
            }
        } else {
            const unsigned short* A = (const unsigned short*)Av;
            #pragma unroll
            for (int i = 0; i < 4; ++i) {
                int idx = tid + i * 256;
                int row = idx >> 3;
                int c8  = idx & 7;
                int4 v = *reinterpret_cast<const int4*>(
                    &A[(size_t)(m0 + row) * K + k0 + c8 * 8]);
                *reinterpret_cast<int4*>(&As[row][c8 * 8]) = v;
            }
        }
        #pragma unroll
        for (int i = 0; i < 8; ++i) {
            int idx = tid + i * 256;
            int row = idx >> 4;
            int c4  = idx & 15;
            float4 w = *reinterpret_cast<const float4*>(
                &W[(size_t)(n0 + row) * K + k0 + c4 * 4]);
            ushort4 o;
            o.x = f2bf(w.x); o.y = f2bf(w.y);
            o.z = f2bf(w.z); o.w = f2bf(w.w);
            *reinterpret_cast<ushort4*>(&Ws[row][c4 * 4]) = o;
        }
        __syncthreads();

        #pragma unroll
        for (int ks = 0; ks < 2; ++ks) {
            bf16x8 af[4], bfr[4];
            #pragma unroll
            for (int i = 0; i < 4; ++i)
                af[i] = *reinterpret_cast<const bf16x8*>(
                    &As[wm * 64 + i * 16 + lr][ks * 32 + lq * 8]);
            #pragma unroll
            for (int j = 0; j < 4; ++j)
                bfr[j] = *reinterpret_cast<const bf16x8*>(
                    &Ws[wn * 64 + j * 16 + lr][ks * 32 + lq * 8]);
            #pragma unroll
            for (int i = 0; i < 4; ++i)
                #pragma unroll
                for (int j = 0; j < 4; ++j)
                    acc[i][j] = __builtin_amdgcn_mfma_f32_16x16x32_bf16(
                        af[i], bfr[j], acc[i][j], 0, 0, 0);
        }
        __syncthreads();
    }

    #pragma unroll
    for (int i = 0; i < 4; ++i) {
        #pragma unroll
        for (int j = 0; j < 4; ++j) {
            int col = n0 + wn * 64 + j * 16 + lr;
            #pragma unroll
            for (int r = 0; r < 4; ++r) {
                int row = m0 + wm * 64 + i * 16 + lq * 4 + r;
                if (C_F32) {
                    ((float*)Cv)[(size_t)row * N + col] = acc[i][j][r];
                } else {
                    ((unsigned short*)Cv)[(size_t)row * N + col] = f2bf(acc[i][j][r]);
                }
            }
        }
    }
}

// ---------------------------------------------------------------------------
// Fixup v2 (unchanged): tail rows via W_ns, streaming coalesced reads.
// ---------------------------------------------------------------------------
__global__ __launch_bounds__(512) void fixup_kernel(
    const float* __restrict__ x,
    const float* __restrict__ Wq_ns,
    const float* __restrict__ Wk_ns,
    const float* __restrict__ Wv_ns,
    unsigned short* __restrict__ Q,
    unsigned short* __restrict__ Kb,
    unsigned short* __restrict__ V)
{
    const int bid   = blockIdx.x;
    const int wgt   = bid >> 6;
    const int chunk = bid & 63;
    const int proj  = wgt >> 3;
    const int n     = wgt & 7;
    const float* Wns =
        (proj == 0 ? Wq_ns : proj == 1 ? Wk_ns : Wv_ns) + (size_t)n * Dsz * Dsz;
    unsigned short* Out = (proj == 0 ? Q : proj == 1 ? Kb : V);
    const int l    = LSsz + n;
    const int b    = threadIdx.x >> 6;
    const int lane = threadIdx.x & 63;

    const float* xrow = x + ((size_t)b * Lsz + l) * Dsz;
    float4 xr[4];
    #pragma unroll
    for (int i = 0; i < 4; ++i)
        xr[i] = *reinterpret_cast<const float4*>(&xrow[lane * 4 + i * 256]);

    for (int er = 0; er < 16; ++er) {
        const int e = chunk * 16 + er;
        const float* wrow = Wns + (size_t)e * Dsz;
        float s = 0.f;
        #pragma unroll
        for (int i = 0; i < 4; ++i) {
            float4 wv = *reinterpret_cast<const float4*>(&wrow[lane * 4 + i * 256]);
            s += wv.x * xr[i].x + wv.y * xr[i].y
               + wv.z * xr[i].z + wv.w * xr[i].w;
        }
        #pragma unroll
        for (int off = 32; off > 0; off >>= 1) s += __shfl_xor(s, off, 64);
        if (lane == 0) Out[((size_t)b * Lsz + l) * Dsz + e] = f2bf(s);
    }
}

// ---------------------------------------------------------------------------
// MFMA flash attention, v2:
//  - 128 q rows per block (2 q-subtiles per wave) -> staging amortized 2x
//  - K staged via global_load_lds into double-buffered LDS with pre-swizzled
//    per-lane SOURCE addresses (linear LDS dest, swizzled read) [m173 pattern]
//  - V prefetched into registers (issue-early / write-late, T14), transposed
//    to LDS with ds_write_b32 pairs instead of 16x ds_write_u16
//  - s_setprio(1) around MFMA clusters (attn-positive per m191)
//  - skip the fully-masked last k-tile for the lower q-subtile
// ---------------------------------------------------------------------------
__global__ __launch_bounds__(256, 4) void attn_mfma_kernel(
    const unsigned short* __restrict__ Q,
    const unsigned short* __restrict__ K,
    const unsigned short* __restrict__ V,
    unsigned short* __restrict__ O)
{
    __shared__ __align__(16) unsigned short Klds[2 * 4096];   // 64x64 dbuf, 16 KB
    __shared__ __align__(16) unsigned short Vtlds[4096];      // 64x64 transposed, 8 KB
    __shared__ __align__(16) unsigned short Plds[4][1024];    // per-wave P, 8 KB

    const int tid  = threadIdx.x;
    const int lane = tid & 63;
    const int wave = tid >> 6;
    const int lr   = lane & 15;
    const int lq   = lane >> 4;

    const int qb = blockIdx.x & 7;        // q-block of 128 rows
    const int bh = blockIdx.x >> 3;
    const int h  = bh & (Hh - 1);
    const int b  = bh >> 4;
    const int nkt = 2 * qb + 2;           // k-tiles needed for upper subtile

    const size_t base = (size_t)b * Lsz * Dsz + (size_t)h * HDsz;

    int qw[2];
    qw[0] = qb * 128 + wave * 16;
    qw[1] = qw[0] + 64;

    // Q fragments for both subtiles, pre-scaled by 1/sqrt(HD)
    bf16x8 qf[2][2];
    #pragma unroll
    for (int s = 0; s < 2; ++s)
        #pragma unroll
        for (int h2 = 0; h2 < 2; ++h2) {
            bf16x8 t = *reinterpret_cast<const bf16x8*>(
                &Q[base + (size_t)(qw[s] + lr) * Dsz + h2 * 32 + lq * 8]);
            #pragma unroll
            for (int e = 0; e < 8; ++e) {
                float f = bf2f((unsigned short)t[e]) * 0.125f;
                t[e] = (short)f2bf(f);
            }
            qf[s][h2] = t;
        }

    f32x4 acc[2][4];
    float m_i[2][4], l_i[2][4];
    #pragma unroll
    for (int s = 0; s < 2; ++s)
        #pragma unroll
        for (int jd = 0; jd < 4; ++jd) {
            acc[s][jd] = (f32x4){0.f, 0.f, 0.f, 0.f};
            m_i[s][jd] = -1e30f;
            l_i[s][jd] = 0.f;
        }

    // staging thread maps
    const int krow0 = tid >> 3;          // K: rows it*32 + krow0
    const int kc8   = tid & 7;           // K: swizzled dest chunk
    const int vd0   = (tid & 7) * 8;     // V: d-chunk base (coalesced inner)
    const int vk0   = (tid >> 3) * 2;    // V: k-row pair base

    unsigned short* Pw = &Plds[wave][0];

    int4 vq0, vq1;

    // ---- prologue: prefetch tile 0 ----
    #pragma unroll
    for (int it = 0; it < 2; ++it) {
        int row  = it * 32 + krow0;
        int csrc = kc8 ^ (row & 7);      // pre-swizzled global source
        const unsigned short* ga = &K[base + (size_t)row * Dsz + csrc * 8];
        __builtin_amdgcn_global_load_lds(GLB(ga),
            LDSP(&Klds[it * 2048 + wave * 512]), 16, 0, 0);
    }
    vq0 = *reinterpret_cast<const int4*>(&V[base + (size_t)(vk0 + 0) * Dsz + vd0]);
    vq1 = *reinterpret_cast<const int4*>(&V[base + (size_t)(vk0 + 1) * Dsz + vd0]);

    for (int kt = 0; kt < nkt; ++kt) {
        const int k0 = kt * 64;
        const int kb = (kt & 1) * 4096;

        __syncthreads();   // prev compute done reading LDS; K(kt) DMA drained

        // write V transpose for current tile (b32 pairs, swizzled)
        {
            union { int4 v; unsigned short u[8]; } a, c;
            a.v = vq0; c.v = vq1;
            const int kc  = vk0 >> 3;
            const int klo = vk0 & 7;
            #pragma unroll
            for (int d = 0; d < 8; ++d) {
                int dd  = vd0 + d;
                int idx = dd * 64 + (((kc ^ (dd & 7)) << 3) | klo);
                ushort2 p; p.x = a.u[d]; p.y = c.u[d];
                *reinterpret_cast<ushort2*>(&Vtlds[idx]) = p;
            }
        }
        __syncthreads();   // Vt visible; all waves in compute phase

        // issue prefetch for next tile (hides under compute)
        if (kt + 1 < nkt) {
            const int k0n = k0 + 64;
            #pragma unroll
            for (int it = 0; it < 2; ++it) {
                int row  = it * 32 + krow0;
                int csrc = kc8 ^ (row & 7);
                const unsigned short* ga =
                    &K[base + (size_t)(k0n + row) * Dsz + csrc * 8];
                __builtin_amdgcn_global_load_lds(GLB(ga),
                    LDSP(&Klds[(kb ^ 4096) + it * 2048 + wave * 512]), 16, 0, 0);
            }
            vq0 = *reinterpret_cast<const int4*>(
                &V[base + (size_t)(k0n + vk0 + 0) * Dsz + vd0]);
            vq1 = *reinterpret_cast<const int4*>(
                &V[base + (size_t)(k0n + vk0 + 1) * Dsz + vd0]);
        }

        // ---- compute both q-subtiles against this K/V tile ----
        #pragma unroll
        for (int s = 0; s < 2; ++s) {
            if (s == 0 && kt == nkt - 1) continue;   // fully masked for lower rows

            f32x4 sv[4];
            #pragma unroll
            for (int jt = 0; jt < 4; ++jt) sv[jt] = (f32x4){0.f, 0.f, 0.f, 0.f};

            __builtin_amdgcn_s_setprio(1);
            #pragma unroll
            for (int h2 = 0; h2 < 2; ++h2) {
                const int cs = (((h2 << 2) | lq) ^ (lr & 7)) << 3;
                #pragma unroll
                for (int jt = 0; jt < 4; ++jt) {
                    bf16x8 kf = *reinterpret_cast<const bf16x8*>(
                        &Klds[kb + (jt * 16 + lr) * 64 + cs]);
                    sv[jt] = __builtin_amdgcn_mfma_f32_16x16x32_bf16(
                        qf[s][h2], kf, sv[jt], 0, 0, 0);
                }
            }
            __builtin_amdgcn_s_setprio(0);

            if (k0 + 63 > qw[s]) {
                #pragma unroll
                for (int jt = 0; jt < 4; ++jt) {
                    int kpos = k0 + jt * 16 + lr;
                    #pragma unroll
                    for (int r = 0; r < 4; ++r) {
                        int q = qw[s] + lq * 4 + r;
                        if (kpos > q) sv[jt][r] = -1e30f;
                    }
                }
            }

            float tm[4], al[4], rs[4];
            #pragma unroll
            for (int r = 0; r < 4; ++r)
                tm[r] = fmaxf(fmaxf(sv[0][r], sv[1][r]), fmaxf(sv[2][r], sv[3][r]));
            #pragma unroll
            for (int off = 1; off < 16; off <<= 1)
                #pragma unroll
                for (int r = 0; r < 4; ++r)
                    tm[r] = fmaxf(tm[r], __shfl_xor(tm[r], off, 64));
            #pragma unroll
            for (int r = 0; r < 4; ++r) {
                float nm = fmaxf(m_i[s][r], tm[r]);
                al[r] = __expf(m_i[s][r] - nm);
                m_i[s][r] = nm;
            }
            #pragma unroll
            for (int jt = 0; jt < 4; ++jt)
                #pragma unroll
                for (int r = 0; r < 4; ++r)
                    sv[jt][r] = __expf(sv[jt][r] - m_i[s][r]);
            #pragma unroll
            for (int r = 0; r < 4; ++r)
                rs[r] = (sv[0][r] + sv[1][r]) + (sv[2][r] + sv[3][r]);
            #pragma unroll
            for (int off = 1; off < 16; off <<= 1)
                #pragma unroll
                for (int r = 0; r < 4; ++r)
                    rs[r] += __shfl_xor(rs[r], off, 64);
            #pragma unroll
            for (int r = 0; r < 4; ++r) l_i[s][r] = l_i[s][r] * al[r] + rs[r];
            #pragma unroll
            for (int jd = 0; jd < 4; ++jd)
                #pragma unroll
                for (int r = 0; r < 4; ++r)
                    acc[s][jd][r] *= al[r];

            #pragma unroll
            for (int jt = 0; jt < 4; ++jt) {
                int kcol  = jt * 16 + lr;
                int chunk = kcol >> 3;
                int elem  = kcol & 7;
                #pragma unroll
                for (int r = 0; r < 4; ++r) {
                    int qrow = lq * 4 + r;
                    Pw[qrow * 64 + (((chunk ^ (qrow & 7)) << 3) | elem)] =
                        f2bf(sv[jt][r]);
                }
            }

            __builtin_amdgcn_s_setprio(1);
            #pragma unroll
            for (int h2 = 0; h2 < 2; ++h2) {
                const int cs = (((h2 << 2) | lq) ^ (lr & 7)) << 3;
                bf16x8 pf = *reinterpret_cast<const bf16x8*>(&Pw[lr * 64 + cs]);
                #pragma unroll
                for (int jd = 0; jd < 4; ++jd) {
                    bf16x8 vf = *reinterpret_cast<const bf16x8*>(
                        &Vtlds[(jd * 16 + lr) * 64 + cs]);
                    acc[s][jd] = __builtin_amdgcn_mfma_f32_16x16x32_bf16(
                        pf, vf, acc[s][jd], 0, 0, 0);
                }
            }
            __builtin_amdgcn_s_setprio(0);
        }
    }

    #pragma unroll
    for (int s = 0; s < 2; ++s)
        #pragma unroll
        for (int r = 0; r < 4; ++r) {
            float inv = 1.0f / l_i[s][r];
            int qrow = qw[s] + lq * 4 + r;
            #pragma unroll
            for (int jd = 0; jd < 4; ++jd)
                O[base + (size_t)qrow * Dsz + jd * 16 + lr] =
                    f2bf(acc[s][jd][r] * inv);
        }
}

// ---------------------------------------------------------------------------
extern "C" void kernel_launch(void* const* d_in, const int* in_sizes, int n_in,
                              void* d_out, int out_size, void* d_ws, size_t ws_size,
                              hipStream_t stream)
{
    const float* x     = (const float*)d_in[0];
    const float* Wq_s  = (const float*)d_in[2];
    const float* Wk_s  = (const float*)d_in[3];
    const float* Wv_s  = (const float*)d_in[4];
    const float* Wq_ns = (const float*)d_in[5];
    const float* Wk_ns = (const float*)d_in[6];
    const float* Wv_ns = (const float*)d_in[7];
    const float* W_out = (const float*)d_in[8];
    float* out = (float*)d_out;

    const size_t nElem = (size_t)Bsz * Lsz * Dsz;            // 8388608
    unsigned short* Q    = (unsigned short*)d_ws;
    unsigned short* Kb   = Q + nElem;
    unsigned short* V    = Kb + nElem;
    unsigned short* Xb   = V + nElem;                        // xb, later O
    unsigned short* Wcat = Xb + nElem;
    unsigned short* Wob  = Wcat + 3 * 1048576;
    const size_t need = (4 * nElem + 4 * 1048576) * sizeof(unsigned short);

    if (ws_size >= need) {
        // ---- fast path: bf16 cast once, async-staged MFMA GEMMs ----
        cast_kernel<<<3072, 256, 0, stream>>>(x, Wq_s, Wk_s, Wv_s, W_out,
                                              Xb, Wcat, Wob);
        gemm_qkv_kernel<<<dim3(24, 64), 256, 0, stream>>>(Xb, Wcat, Q, Kb, V);
        fixup_kernel<<<24 * 64, 512, 0, stream>>>(x, Wq_ns, Wk_ns, Wv_ns, Q, Kb, V);
        unsigned short* O = Xb;   // xb dead after gemm_qkv; reuse for attn out
        attn_mfma_kernel<<<Bsz * Hh * (Lsz / 128), 256, 0, stream>>>(Q, Kb, V, O);
        gemm_obf_kernel<<<dim3(8, 64), 256, 0, stream>>>(O, Wob, out);
    } else {
        // ---- fallback (round-5 path), needs only 4*nElem*2 bytes ----
        unsigned short* O = Xb;
        dim3 ggrid(Dsz / GBN, (Bsz * Lsz) / GBM);
        gemm_bt_kernel<true, false><<<ggrid, 256, 0, stream>>>(x, Wq_s, Q,  Bsz * Lsz, Dsz, Dsz);
        gemm_bt_kernel<true, false><<<ggrid, 256, 0, stream>>>(x, Wk_s, Kb, Bsz * Lsz, Dsz, Dsz);
        gemm_bt_kernel<true, false><<<ggrid, 256, 0, stream>>>(x, Wv_s, V,  Bsz * Lsz, Dsz, Dsz);
        fixup_kernel<<<24 * 64, 512, 0, stream>>>(x, Wq_ns, Wk_ns, Wv_ns, Q, Kb, V);
        attn_mfma_kernel<<<Bsz * Hh * (Lsz / 128), 256, 0, stream>>>(Q, Kb, V, O);
        gemm_bt_kernel<false, true><<<ggrid, 256, 0, stream>>>(O, W_out, out, Bsz * Lsz, Dsz, Dsz);
    }
}

// Round 2
// 389.817 us; speedup vs baseline: 1.3176x; 1.3176x over previous
//
#include <hip/hip_runtime.h>

// Problem constants (B,L,D,H fixed from reference)
#define Bsz  8
#define Lsz  1024
#define Dsz  1024
#define Hh   16
#define HDsz 64
#define NSsz 8
#define LSsz 1016

typedef short  bf16x8 __attribute__((ext_vector_type(8)));   // 8 bf16 (4 VGPRs)
typedef float  f32x4  __attribute__((ext_vector_type(4)));

#define GLB(p) ((const __attribute__((address_space(1))) unsigned int*)(p))
#define LDSP(p) ((__attribute__((address_space(3))) unsigned int*)(p))

__device__ __forceinline__ float bf2f(unsigned short u) {
    union { unsigned int i; float f; } v; v.i = ((unsigned int)u) << 16; return v.f;
}
__device__ __forceinline__ unsigned short f2bf(float f) {
    union { float f; unsigned int i; } v; v.f = f;
    unsigned int x = v.i;
    return (unsigned short)((x + 0x7FFFu + ((x >> 16) & 1u)) >> 16);
}

// ---------------------------------------------------------------------------
// Cast kernel: x (fp32) -> xb (bf16); Wq_s|Wk_s|Wv_s -> Wcat; W_out -> Wob.
// ---------------------------------------------------------------------------
__global__ __launch_bounds__(256) void cast_kernel(
    const float* __restrict__ x,
    const float* __restrict__ wq, const float* __restrict__ wk,
    const float* __restrict__ wv, const float* __restrict__ wo,
    unsigned short* __restrict__ xb,
    unsigned short* __restrict__ wcat,
    unsigned short* __restrict__ wob)
{
    const size_t NX = 2097152;   // float4s in x (8388608 elems)
    const size_t NW = 262144;    // float4s per DxD weight
    size_t i = (size_t)blockIdx.x * 256 + threadIdx.x;
    const size_t stride = (size_t)gridDim.x * 256;
    const size_t total = NX + 4 * NW;
    for (; i < total; i += stride) {
        const float* src; unsigned short* dst; size_t off;
        if (i < NX)               { src = x;  dst = xb;             off = i; }
        else if (i < NX + NW)     { src = wq; dst = wcat;           off = i - NX; }
        else if (i < NX + 2 * NW) { src = wk; dst = wcat + 1048576; off = i - NX - NW; }
        else if (i < NX + 3 * NW) { src = wv; dst = wcat + 2097152; off = i - NX - 2 * NW; }
        else                      { src = wo; dst = wob;            off = i - NX - 3 * NW; }
        float4 v = reinterpret_cast<const float4*>(src)[off];
        ushort4 o;
        o.x = f2bf(v.x); o.y = f2bf(v.y); o.z = f2bf(v.z); o.w = f2bf(v.w);
        reinterpret_cast<ushort4*>(dst)[off] = o;
    }
}

// ---------------------------------------------------------------------------
// Fused QKV GEMM (m97-style): [8192 x 3072] = xb[8192x1024] @ Wcat[3072x1024]^T
// ---------------------------------------------------------------------------
__global__ __launch_bounds__(256) void gemm_qkv_kernel(
    const unsigned short* __restrict__ Ab,
    const unsigned short* __restrict__ Wb,
    unsigned short* __restrict__ Qo,
    unsigned short* __restrict__ Ko,
    unsigned short* __restrict__ Vo)
{
    __shared__ __align__(16) unsigned short As[128 * 64];  // 16 KB
    __shared__ __align__(16) unsigned short Bs[128 * 64];  // 16 KB

    const int tid  = threadIdx.x;
    const int lane = tid & 63;
    const int wave = tid >> 6;
    const int wm   = wave >> 1;
    const int wn   = wave & 1;
    const int lr   = lane & 15;
    const int lq   = lane >> 4;
    const int m0   = blockIdx.y * 128;
    const int n0   = blockIdx.x * 128;

    const int lrow = lane >> 3;          // 0..7
    const int lcol = (lane & 7) << 3;    // 0..56

    f32x4 acc[4][4];
    #pragma unroll
    for (int i = 0; i < 4; ++i)
        #pragma unroll
        for (int j = 0; j < 4; ++j)
            acc[i][j] = (f32x4){0.f, 0.f, 0.f, 0.f};

    for (int k0 = 0; k0 < 1024; k0 += 64) {
        #pragma unroll
        for (int it = 0; it < 4; ++it) {
            int row = it * 32 + wave * 8 + lrow;
            const unsigned short* ga = &Ab[(size_t)(m0 + row) * 1024 + k0 + lcol];
            const unsigned short* gb = &Wb[(size_t)(n0 + row) * 1024 + k0 + lcol];
            __builtin_amdgcn_global_load_lds(GLB(ga), LDSP(&As[it * 2048 + wave * 512]), 16, 0, 0);
            __builtin_amdgcn_global_load_lds(GLB(gb), LDSP(&Bs[it * 2048 + wave * 512]), 16, 0, 0);
        }
        __syncthreads();

        #pragma unroll
        for (int ks = 0; ks < 2; ++ks) {
            bf16x8 af[4], bfr[4];
            #pragma unroll
            for (int i = 0; i < 4; ++i)
                af[i] = *reinterpret_cast<const bf16x8*>(
                    &As[(wm * 64 + i * 16 + lr) * 64 + ks * 32 + lq * 8]);
            #pragma unroll
            for (int j = 0; j < 4; ++j)
                bfr[j] = *reinterpret_cast<const bf16x8*>(
                    &Bs[(wn * 64 + j * 16 + lr) * 64 + ks * 32 + lq * 8]);
            #pragma unroll
            for (int i = 0; i < 4; ++i)
                #pragma unroll
                for (int j = 0; j < 4; ++j)
                    acc[i][j] = __builtin_amdgcn_mfma_f32_16x16x32_bf16(
                        af[i], bfr[j], acc[i][j], 0, 0, 0);
        }
        __syncthreads();
    }

    const int t  = n0 >> 10;                 // uniform per block
    const int d0 = n0 & 1023;
    unsigned short* Out = (t == 0 ? Qo : t == 1 ? Ko : Vo);
    #pragma unroll
    for (int i = 0; i < 4; ++i) {
        #pragma unroll
        for (int j = 0; j < 4; ++j) {
            int col = d0 + wn * 64 + j * 16 + lr;
            #pragma unroll
            for (int r = 0; r < 4; ++r) {
                int row = m0 + wm * 64 + i * 16 + lq * 4 + r;
                Out[(size_t)row * 1024 + col] = f2bf(acc[i][j][r]);
            }
        }
    }
}

// ---------------------------------------------------------------------------
// Final projection GEMM: out[8192x1024] fp32 = Ob[8192x1024] @ Wob[1024x1024]^T
// ---------------------------------------------------------------------------
__global__ __launch_bounds__(256) void gemm_obf_kernel(
    const unsigned short* __restrict__ Ab,
    const unsigned short* __restrict__ Wb,
    float* __restrict__ Co)
{
    __shared__ __align__(16) unsigned short As[128 * 64];
    __shared__ __align__(16) unsigned short Bs[128 * 64];

    const int tid  = threadIdx.x;
    const int lane = tid & 63;
    const int wave = tid >> 6;
    const int wm   = wave >> 1;
    const int wn   = wave & 1;
    const int lr   = lane & 15;
    const int lq   = lane >> 4;
    const int m0   = blockIdx.y * 128;
    const int n0   = blockIdx.x * 128;

    const int lrow = lane >> 3;
    const int lcol = (lane & 7) << 3;

    f32x4 acc[4][4];
    #pragma unroll
    for (int i = 0; i < 4; ++i)
        #pragma unroll
        for (int j = 0; j < 4; ++j)
            acc[i][j] = (f32x4){0.f, 0.f, 0.f, 0.f};

    for (int k0 = 0; k0 < 1024; k0 += 64) {
        #pragma unroll
        for (int it = 0; it < 4; ++it) {
            int row = it * 32 + wave * 8 + lrow;
            const unsigned short* ga = &Ab[(size_t)(m0 + row) * 1024 + k0 + lcol];
            const unsigned short* gb = &Wb[(size_t)(n0 + row) * 1024 + k0 + lcol];
            __builtin_amdgcn_global_load_lds(GLB(ga), LDSP(&As[it * 2048 + wave * 512]), 16, 0, 0);
            __builtin_amdgcn_global_load_lds(GLB(gb), LDSP(&Bs[it * 2048 + wave * 512]), 16, 0, 0);
        }
        __syncthreads();

        #pragma unroll
        for (int ks = 0; ks < 2; ++ks) {
            bf16x8 af[4], bfr[4];
            #pragma unroll
            for (int i = 0; i < 4; ++i)
                af[i] = *reinterpret_cast<const bf16x8*>(
                    &As[(wm * 64 + i * 16 + lr) * 64 + ks * 32 + lq * 8]);
            #pragma unroll
            for (int j = 0; j < 4; ++j)
                bfr[j] = *reinterpret_cast<const bf16x8*>(
                    &Bs[(wn * 64 + j * 16 + lr) * 64 + ks * 32 + lq * 8]);
            #pragma unroll
            for (int i = 0; i < 4; ++i)
                #pragma unroll
                for (int j = 0; j < 4; ++j)
                    acc[i][j] = __builtin_amdgcn_mfma_f32_16x16x32_bf16(
                        af[i], bfr[j], acc[i][j], 0, 0, 0);
        }
        __syncthreads();
    }

    #pragma unroll
    for (int i = 0; i < 4; ++i) {
        #pragma unroll
        for (int j = 0; j < 4; ++j) {
            int col = n0 + wn * 64 + j * 16 + lr;
            #pragma unroll
            for (int r = 0; r < 4; ++r) {
                int row = m0 + wm * 64 + i * 16 + lq * 4 + r;
                Co[(size_t)row * 1024 + col] = acc[i][j][r];
            }
        }
    }
}

// ---------------------------------------------------------------------------
// Fallback GEMM (round-5 structure): C = A @ W^T, fp32 W staged via VGPRs.
// ---------------------------------------------------------------------------
#define GBM 128
#define GBN 128
#define GBK 64

template <bool A_F32, bool C_F32>
__global__ __launch_bounds__(256) void gemm_bt_kernel(
    const void* __restrict__ Av,
    const float* __restrict__ W,
    void* __restrict__ Cv,
    int M, int N, int K)
{
    __shared__ unsigned short As[GBM][GBK];
    __shared__ unsigned short Ws[GBN][GBK];

    const int tid  = threadIdx.x;
    const int lane = tid & 63;
    const int wave = tid >> 6;
    const int wm   = wave >> 1;
    const int wn   = wave & 1;
    const int lr   = lane & 15;
    const int lq   = lane >> 4;
    const int m0   = blockIdx.y * GBM;
    const int n0   = blockIdx.x * GBN;

    f32x4 acc[4][4];
    #pragma unroll
    for (int i = 0; i < 4; ++i)
        #pragma unroll
        for (int j = 0; j < 4; ++j)
            acc[i][j] = (f32x4){0.f, 0.f, 0.f, 0.f};

    for (int k0 = 0; k0 < K; k0 += GBK) {
        if (A_F32) {
            const float* A = (const float*)Av;
            #pragma unroll
            for (int i = 0; i < 8; ++i) {
                int idx = tid + i * 256;
                int row = idx >> 4;
                int c4  = idx & 15;
                float4 a = *reinterpret_cast<const float4*>(
                    &A[(size_t)(m0 + row) * K + k0 + c4 * 4]);
                ushort4 o;
                o.x = f2bf(a.x); o.y = f2bf(a.y);
                o.z = f2bf(a.z); o.w = f2bf(a.w);
                *reinterpret_cast<ushort4*>(&As[row][c4 * 4]) = o;
            }
        } else {
            const unsigned short* A = (const unsigned short*)Av;
            #pragma unroll
            for (int i = 0; i < 4; ++i) {
                int idx = tid + i * 256;
                int row = idx >> 3;
                int c8  = idx & 7;
                int4 v = *reinterpret_cast<const int4*>(
                    &A[(size_t)(m0 + row) * K + k0 + c8 * 8]);
                *reinterpret_cast<int4*>(&As[row][c8 * 8]) = v;
            }
        }
        #pragma unroll
        for (int i = 0; i < 8; ++i) {
            int idx = tid + i * 256;
            int row = idx >> 4;
            int c4  = idx & 15;
            float4 w = *reinterpret_cast<const float4*>(
                &W[(size_t)(n0 + row) * K + k0 + c4 * 4]);
            ushort4 o;
            o.x = f2bf(w.x); o.y = f2bf(w.y);
            o.z = f2bf(w.z); o.w = f2bf(w.w);
            *reinterpret_cast<ushort4*>(&Ws[row][c4 * 4]) = o;
        }
        __syncthreads();

        #pragma unroll
        for (int ks = 0; ks < 2; ++ks) {
            bf16x8 af[4], bfr[4];
            #pragma unroll
            for (int i = 0; i < 4; ++i)
                af[i] = *reinterpret_cast<const bf16x8*>(
                    &As[wm * 64 + i * 16 + lr][ks * 32 + lq * 8]);
            #pragma unroll
            for (int j = 0; j < 4; ++j)
                bfr[j] = *reinterpret_cast<const bf16x8*>(
                    &Ws[wn * 64 + j * 16 + lr][ks * 32 + lq * 8]);
            #pragma unroll
            for (int i = 0; i < 4; ++i)
                #pragma unroll
                for (int j = 0; j < 4; ++j)
                    acc[i][j] = __builtin_amdgcn_mfma_f32_16x16x32_bf16(
                        af[i], bfr[j], acc[i][j], 0, 0, 0);
        }
        __syncthreads();
    }

    #pragma unroll
    for (int i = 0; i < 4; ++i) {
        #pragma unroll
        for (int j = 0; j < 4; ++j) {
            int col = n0 + wn * 64 + j * 16 + lr;
            #pragma unroll
            for (int r = 0; r < 4; ++r) {
                int row = m0 + wm * 64 + i * 16 + lq * 4 + r;
                if (C_F32) {
                    ((float*)Cv)[(size_t)row * N + col] = acc[i][j][r];
                } else {
                    ((unsigned short*)Cv)[(size_t)row * N + col] = f2bf(acc[i][j][r]);
                }
            }
        }
    }
}

// ---------------------------------------------------------------------------
// Fixup v2 (unchanged): tail rows via W_ns, streaming coalesced reads.
// ---------------------------------------------------------------------------
__global__ __launch_bounds__(512) void fixup_kernel(
    const float* __restrict__ x,
    const float* __restrict__ Wq_ns,
    const float* __restrict__ Wk_ns,
    const float* __restrict__ Wv_ns,
    unsigned short* __restrict__ Q,
    unsigned short* __restrict__ Kb,
    unsigned short* __restrict__ V)
{
    const int bid   = blockIdx.x;
    const int wgt   = bid >> 6;
    const int chunk = bid & 63;
    const int proj  = wgt >> 3;
    const int n     = wgt & 7;
    const float* Wns =
        (proj == 0 ? Wq_ns : proj == 1 ? Wk_ns : Wv_ns) + (size_t)n * Dsz * Dsz;
    unsigned short* Out = (proj == 0 ? Q : proj == 1 ? Kb : V);
    const int l    = LSsz + n;
    const int b    = threadIdx.x >> 6;
    const int lane = threadIdx.x & 63;

    const float* xrow = x + ((size_t)b * Lsz + l) * Dsz;
    float4 xr[4];
    #pragma unroll
    for (int i = 0; i < 4; ++i)
        xr[i] = *reinterpret_cast<const float4*>(&xrow[lane * 4 + i * 256]);

    for (int er = 0; er < 16; ++er) {
        const int e = chunk * 16 + er;
        const float* wrow = Wns + (size_t)e * Dsz;
        float s = 0.f;
        #pragma unroll
        for (int i = 0; i < 4; ++i) {
            float4 wv = *reinterpret_cast<const float4*>(&wrow[lane * 4 + i * 256]);
            s += wv.x * xr[i].x + wv.y * xr[i].y
               + wv.z * xr[i].z + wv.w * xr[i].w;
        }
        #pragma unroll
        for (int off = 32; off > 0; off >>= 1) s += __shfl_xor(s, off, 64);
        if (lane == 0) Out[((size_t)b * Lsz + l) * Dsz + e] = f2bf(s);
    }
}

// ---------------------------------------------------------------------------
// MFMA flash attention, v3: v1 geometry (2048 blocks, 64 q-rows, wave=16 rows)
// + v2 latency-hiding:
//  - K via global_load_lds, double-buffered, pre-swizzled source, prefetch
//    issued before compute (hidden under previous tile's MFMA/softmax)
//  - V reg-prefetched (2x int4/thread), swizzled ds_write_b32 pairs
//  - XCD swizzle: all 16 q-tiles of one (b,h) on one XCD (K/V L2-resident);
//    heavy q-tiles launch first (short blocks form the tail)
//  - coalesced O epilogue via LDS bounce (int4 stores, no partial lines)
//  - s_setprio(1) around MFMA clusters
// ---------------------------------------------------------------------------
__global__ __launch_bounds__(256, 4) void attn_mfma_kernel(
    const unsigned short* __restrict__ Q,
    const unsigned short* __restrict__ K,
    const unsigned short* __restrict__ V,
    unsigned short* __restrict__ O)
{
    __shared__ __align__(16) unsigned short Klds[2 * 4096];   // 64x64 dbuf, 16 KB
    __shared__ __align__(16) unsigned short Vtlds[4096];      // 64x64 transposed, 8 KB
    __shared__ __align__(16) unsigned short Plds[4][1024];    // per-wave P + O bounce, 8 KB

    const int tid  = threadIdx.x;
    const int lane = tid & 63;
    const int wave = tid >> 6;
    const int lr   = lane & 15;
    const int lq   = lane >> 4;

    // XCD-aware mapping: xcd = id & 7 = bh & 7 (all q-tiles of a bh share L2).
    // qt reversed so heaviest blocks (qt=15) have the lowest ids -> launch first.
    const int id = blockIdx.x;
    const int qt = 15 - ((id >> 3) & 15);
    const int bh = ((id >> 7) << 3) | (id & 7);
    const int h  = bh & (Hh - 1);
    const int b  = bh >> 4;
    const int qw = qt * 64 + wave * 16;
    const int nkt = qt + 1;

    const size_t base = (size_t)b * Lsz * Dsz + (size_t)h * HDsz;

    // Q fragments, pre-scaled by 1/sqrt(HD)
    bf16x8 qf[2];
    #pragma unroll
    for (int h2 = 0; h2 < 2; ++h2) {
        bf16x8 t = *reinterpret_cast<const bf16x8*>(
            &Q[base + (size_t)(qw + lr) * Dsz + h2 * 32 + lq * 8]);
        #pragma unroll
        for (int e = 0; e < 8; ++e) {
            float f = bf2f((unsigned short)t[e]) * 0.125f;
            t[e] = (short)f2bf(f);
        }
        qf[h2] = t;
    }

    f32x4 acc[4];
    #pragma unroll
    for (int jd = 0; jd < 4; ++jd) acc[jd] = (f32x4){0.f, 0.f, 0.f, 0.f};
    float m_i[4] = {-1e30f, -1e30f, -1e30f, -1e30f};
    float l_i[4] = {0.f, 0.f, 0.f, 0.f};

    // staging thread maps
    const int krow0 = tid >> 3;          // K rows: it*32 + krow0
    const int kc8   = tid & 7;           // K dest chunk (linear LDS)
    const int vd0   = (tid & 7) * 8;     // V d-chunk base (coalesced inner)
    const int vk0   = (tid >> 3) * 2;    // V k-row pair base

    unsigned short* Pw = &Plds[wave][0];
    int4 vq0, vq1;

    // ---- prologue: prefetch tile 0 ----
    #pragma unroll
    for (int it = 0; it < 2; ++it) {
        int row  = it * 32 + krow0;
        int csrc = kc8 ^ (row & 7);      // pre-swizzled global source
        const unsigned short* ga = &K[base + (size_t)row * Dsz + csrc * 8];
        __builtin_amdgcn_global_load_lds(GLB(ga),
            LDSP(&Klds[it * 2048 + wave * 512]), 16, 0, 0);
    }
    vq0 = *reinterpret_cast<const int4*>(&V[base + (size_t)(vk0 + 0) * Dsz + vd0]);
    vq1 = *reinterpret_cast<const int4*>(&V[base + (size_t)(vk0 + 1) * Dsz + vd0]);

    for (int kt = 0; kt < nkt; ++kt) {
        const int k0 = kt * 64;
        const int kb = (kt & 1) * 4096;

        __syncthreads();   // drains K(kt) DMA + V regs; prev compute done

        // V transpose write (b32 pairs, swizzled)
        {
            union { int4 v; unsigned short u[8]; } a, c;
            a.v = vq0; c.v = vq1;
            const int kc  = vk0 >> 3;
            const int klo = vk0 & 7;
            #pragma unroll
            for (int d = 0; d < 8; ++d) {
                int dd  = vd0 + d;
                int idx = dd * 64 + (((kc ^ (dd & 7)) << 3) | klo);
                ushort2 p; p.x = a.u[d]; p.y = c.u[d];
                *reinterpret_cast<ushort2*>(&Vtlds[idx]) = p;
            }
        }
        __syncthreads();   // Vt visible

        // issue prefetch for next tile (in flight across compute)
        if (kt + 1 < nkt) {
            const int k0n = k0 + 64;
            #pragma unroll
            for (int it = 0; it < 2; ++it) {
                int row  = it * 32 + krow0;
                int csrc = kc8 ^ (row & 7);
                const unsigned short* ga =
                    &K[base + (size_t)(k0n + row) * Dsz + csrc * 8];
                __builtin_amdgcn_global_load_lds(GLB(ga),
                    LDSP(&Klds[(kb ^ 4096) + it * 2048 + wave * 512]), 16, 0, 0);
            }
            vq0 = *reinterpret_cast<const int4*>(
                &V[base + (size_t)(k0n + vk0 + 0) * Dsz + vd0]);
            vq1 = *reinterpret_cast<const int4*>(
                &V[base + (size_t)(k0n + vk0 + 1) * Dsz + vd0]);
        }

        // ---- QK^T ----
        f32x4 sv[4];
        #pragma unroll
        for (int jt = 0; jt < 4; ++jt) sv[jt] = (f32x4){0.f, 0.f, 0.f, 0.f};

        __builtin_amdgcn_s_setprio(1);
        #pragma unroll
        for (int h2 = 0; h2 < 2; ++h2) {
            const int cs = (((h2 << 2) | lq) ^ (lr & 7)) << 3;
            #pragma unroll
            for (int jt = 0; jt < 4; ++jt) {
                bf16x8 kf = *reinterpret_cast<const bf16x8*>(
                    &Klds[kb + (jt * 16 + lr) * 64 + cs]);
                sv[jt] = __builtin_amdgcn_mfma_f32_16x16x32_bf16(
                    qf[h2], kf, sv[jt], 0, 0, 0);
            }
        }
        __builtin_amdgcn_s_setprio(0);

        if (k0 + 63 > qw) {
            #pragma unroll
            for (int jt = 0; jt < 4; ++jt) {
                int kpos = k0 + jt * 16 + lr;
                #pragma unroll
                for (int r = 0; r < 4; ++r) {
                    int q = qw + lq * 4 + r;
                    if (kpos > q) sv[jt][r] = -1e30f;
                }
            }
        }

        // ---- online softmax ----
        float tm[4], al[4], rs[4];
        #pragma unroll
        for (int r = 0; r < 4; ++r)
            tm[r] = fmaxf(fmaxf(sv[0][r], sv[1][r]), fmaxf(sv[2][r], sv[3][r]));
        #pragma unroll
        for (int off = 1; off < 16; off <<= 1)
            #pragma unroll
            for (int r = 0; r < 4; ++r)
                tm[r] = fmaxf(tm[r], __shfl_xor(tm[r], off, 64));
        #pragma unroll
        for (int r = 0; r < 4; ++r) {
            float nm = fmaxf(m_i[r], tm[r]);
            al[r] = __expf(m_i[r] - nm);
            m_i[r] = nm;
        }
        #pragma unroll
        for (int jt = 0; jt < 4; ++jt)
            #pragma unroll
            for (int r = 0; r < 4; ++r)
                sv[jt][r] = __expf(sv[jt][r] - m_i[r]);
        #pragma unroll
        for (int r = 0; r < 4; ++r)
            rs[r] = (sv[0][r] + sv[1][r]) + (sv[2][r] + sv[3][r]);
        #pragma unroll
        for (int off = 1; off < 16; off <<= 1)
            #pragma unroll
            for (int r = 0; r < 4; ++r)
                rs[r] += __shfl_xor(rs[r], off, 64);
        #pragma unroll
        for (int r = 0; r < 4; ++r) l_i[r] = l_i[r] * al[r] + rs[r];
        #pragma unroll
        for (int jd = 0; jd < 4; ++jd)
            #pragma unroll
            for (int r = 0; r < 4; ++r)
                acc[jd][r] *= al[r];

        // ---- P -> LDS (swizzled), PV ----
        #pragma unroll
        for (int jt = 0; jt < 4; ++jt) {
            int kcol  = jt * 16 + lr;
            int chunk = kcol >> 3;
            int elem  = kcol & 7;
            #pragma unroll
            for (int r = 0; r < 4; ++r) {
                int qrow = lq * 4 + r;
                Pw[qrow * 64 + (((chunk ^ (qrow & 7)) << 3) | elem)] =
                    f2bf(sv[jt][r]);
            }
        }

        __builtin_amdgcn_s_setprio(1);
        #pragma unroll
        for (int h2 = 0; h2 < 2; ++h2) {
            const int cs = (((h2 << 2) | lq) ^ (lr & 7)) << 3;
            bf16x8 pf = *reinterpret_cast<const bf16x8*>(&Pw[lr * 64 + cs]);
            #pragma unroll
            for (int jd = 0; jd < 4; ++jd) {
                bf16x8 vf = *reinterpret_cast<const bf16x8*>(
                    &Vtlds[(jd * 16 + lr) * 64 + cs]);
                acc[jd] = __builtin_amdgcn_mfma_f32_16x16x32_bf16(
                    pf, vf, acc[jd], 0, 0, 0);
            }
        }
        __builtin_amdgcn_s_setprio(0);
    }

    // ---- epilogue: coalesced O via per-wave LDS bounce ----
    float inv[4];
    #pragma unroll
    for (int r = 0; r < 4; ++r) inv[r] = 1.0f / l_i[r];
    #pragma unroll
    for (int jd = 0; jd < 4; ++jd) {
        #pragma unroll
        for (int r = 0; r < 4; ++r) {
            int qrow  = lq * 4 + r;
            int col   = jd * 16 + lr;
            int chunk = col >> 3;
            int elem  = col & 7;
            Pw[qrow * 64 + (((chunk ^ (qrow & 7)) << 3) | elem)] =
                f2bf(acc[jd][r] * inv[r]);
        }
    }
    // same-wave LDS readback, no barrier needed
    #pragma unroll
    for (int it2 = 0; it2 < 2; ++it2) {
        int row = it2 * 8 + (lane >> 3);
        int c   = lane & 7;
        const int4 ov = *reinterpret_cast<const int4*>(
            &Pw[row * 64 + ((c ^ (row & 7)) << 3)]);
        *reinterpret_cast<int4*>(&O[base + (size_t)(qw + row) * Dsz + c * 8]) = ov;
    }
}

// ---------------------------------------------------------------------------
extern "C" void kernel_launch(void* const* d_in, const int* in_sizes, int n_in,
                              void* d_out, int out_size, void* d_ws, size_t ws_size,
                              hipStream_t stream)
{
    const float* x     = (const float*)d_in[0];
    const float* Wq_s  = (const float*)d_in[2];
    const float* Wk_s  = (const float*)d_in[3];
    const float* Wv_s  = (const float*)d_in[4];
    const float* Wq_ns = (const float*)d_in[5];
    const float* Wk_ns = (const float*)d_in[6];
    const float* Wv_ns = (const float*)d_in[7];
    const float* W_out = (const float*)d_in[8];
    float* out = (float*)d_out;

    const size_t nElem = (size_t)Bsz * Lsz * Dsz;            // 8388608
    unsigned short* Q    = (unsigned short*)d_ws;
    unsigned short* Kb   = Q + nElem;
    unsigned short* V    = Kb + nElem;
    unsigned short* Xb   = V + nElem;                        // xb, later O
    unsigned short* Wcat = Xb + nElem;
    unsigned short* Wob  = Wcat + 3 * 1048576;
    const size_t need = (4 * nElem + 4 * 1048576) * sizeof(unsigned short);

    if (ws_size >= need) {
        // ---- fast path: bf16 cast once, async-staged MFMA GEMMs ----
        cast_kernel<<<3072, 256, 0, stream>>>(x, Wq_s, Wk_s, Wv_s, W_out,
                                              Xb, Wcat, Wob);
        gemm_qkv_kernel<<<dim3(24, 64), 256, 0, stream>>>(Xb, Wcat, Q, Kb, V);
        fixup_kernel<<<24 * 64, 512, 0, stream>>>(x, Wq_ns, Wk_ns, Wv_ns, Q, Kb, V);
        unsigned short* O = Xb;   // xb dead after gemm_qkv; reuse for attn out
        attn_mfma_kernel<<<Bsz * Hh * (Lsz / 64), 256, 0, stream>>>(Q, Kb, V, O);
        gemm_obf_kernel<<<dim3(8, 64), 256, 0, stream>>>(O, Wob, out);
    } else {
        // ---- fallback (round-5 path), needs only 4*nElem*2 bytes ----
        unsigned short* O = Xb;
        dim3 ggrid(Dsz / GBN, (Bsz * Lsz) / GBM);
        gemm_bt_kernel<true, false><<<ggrid, 256, 0, stream>>>(x, Wq_s, Q,  Bsz * Lsz, Dsz, Dsz);
        gemm_bt_kernel<true, false><<<ggrid, 256, 0, stream>>>(x, Wk_s, Kb, Bsz * Lsz, Dsz, Dsz);
        gemm_bt_kernel<true, false><<<ggrid, 256, 0, stream>>>(x, Wv_s, V,  Bsz * Lsz, Dsz, Dsz);
        fixup_kernel<<<24 * 64, 512, 0, stream>>>(x, Wq_ns, Wk_ns, Wv_ns, Q, Kb, V);
        attn_mfma_kernel<<<Bsz * Hh * (Lsz / 64), 256, 0, stream>>>(Q, Kb, V, O);
        gemm_bt_kernel<false, true><<<ggrid, 256, 0, stream>>>(O, W_out, out, Bsz * Lsz, Dsz, Dsz);
    }
}

// Round 3
// 388.046 us; speedup vs baseline: 1.3236x; 1.0046x over previous
//
#include <hip/hip_runtime.h>

// Problem constants (B,L,D,H fixed from reference)
#define Bsz  8
#define Lsz  1024
#define Dsz  1024
#define Hh   16
#define HDsz 64
#define NSsz 8
#define LSsz 1016

typedef short  bf16x8 __attribute__((ext_vector_type(8)));   // 8 bf16 (4 VGPRs)
typedef float  f32x4  __attribute__((ext_vector_type(4)));

#define GLB(p) ((const __attribute__((address_space(1))) unsigned int*)(p))
#define LDSP(p) ((__attribute__((address_space(3))) unsigned int*)(p))

__device__ __forceinline__ float bf2f(unsigned short u) {
    union { unsigned int i; float f; } v; v.i = ((unsigned int)u) << 16; return v.f;
}
__device__ __forceinline__ unsigned short f2bf(float f) {
    union { float f; unsigned int i; } v; v.f = f;
    unsigned int x = v.i;
    return (unsigned short)((x + 0x7FFFu + ((x >> 16) & 1u)) >> 16);
}

// ---------------------------------------------------------------------------
// Cast kernel: x (fp32) -> xb (bf16); Wq_s|Wk_s|Wv_s -> Wcat; W_out -> Wob.
// ---------------------------------------------------------------------------
__global__ __launch_bounds__(256) void cast_kernel(
    const float* __restrict__ x,
    const float* __restrict__ wq, const float* __restrict__ wk,
    const float* __restrict__ wv, const float* __restrict__ wo,
    unsigned short* __restrict__ xb,
    unsigned short* __restrict__ wcat,
    unsigned short* __restrict__ wob)
{
    const size_t NX = 2097152;   // float4s in x (8388608 elems)
    const size_t NW = 262144;    // float4s per DxD weight
    size_t i = (size_t)blockIdx.x * 256 + threadIdx.x;
    const size_t stride = (size_t)gridDim.x * 256;
    const size_t total = NX + 4 * NW;
    for (; i < total; i += stride) {
        const float* src; unsigned short* dst; size_t off;
        if (i < NX)               { src = x;  dst = xb;             off = i; }
        else if (i < NX + NW)     { src = wq; dst = wcat;           off = i - NX; }
        else if (i < NX + 2 * NW) { src = wk; dst = wcat + 1048576; off = i - NX - NW; }
        else if (i < NX + 3 * NW) { src = wv; dst = wcat + 2097152; off = i - NX - 2 * NW; }
        else                      { src = wo; dst = wob;            off = i - NX - 3 * NW; }
        float4 v = reinterpret_cast<const float4*>(src)[off];
        ushort4 o;
        o.x = f2bf(v.x); o.y = f2bf(v.y); o.z = f2bf(v.z); o.w = f2bf(v.w);
        reinterpret_cast<ushort4*>(dst)[off] = o;
    }
}

// ---------------------------------------------------------------------------
// Pipelined GEMM (T3+T4+T5): C = A[M x 1024] @ W[N x 1024]^T, bf16 inputs.
// BM=256, BN=128, BK=64; 8 waves (2M x 4N), 512 threads; per-wave 128x32.
// Triple-buffered LDS (144 KB), ONE raw s_barrier per K-tile, counted
// vmcnt(6) (never 0 until tail), stage issued 2 tiles ahead, swizzled
// global_load_lds source (linear LDS dest, XOR-swizzled read), setprio
// around the MFMA clusters.
// SPLIT: output cols [0,1024)->O0, [1024,2048)->O1, [2048,3072)->O2 (bf16).
// else: single f32 output O0.
// ---------------------------------------------------------------------------
#define STAGE3(tt) do {                                                         \
    const int _k0 = (tt) * 64;                                                  \
    unsigned short* _Ad = &As[((tt) % 3) * 16384 + wave * 512];                 \
    unsigned short* _Bd = &Bs[((tt) % 3) * 8192  + wave * 512];                 \
    _Pragma("unroll")                                                           \
    for (int _it = 0; _it < 4; ++_it) {                                         \
        int _r = _it * 64 + srow;                                               \
        int _c = sc8 ^ (_r & 7);                                                \
        __builtin_amdgcn_global_load_lds(                                       \
            GLB(&Ab[(size_t)(m0 + _r) * 1024 + _k0 + _c * 8]),                  \
            LDSP(_Ad + _it * 4096), 16, 0, 0);                                  \
    }                                                                           \
    _Pragma("unroll")                                                           \
    for (int _it = 0; _it < 2; ++_it) {                                         \
        int _r = _it * 64 + srow;                                               \
        int _c = sc8 ^ (_r & 7);                                                \
        __builtin_amdgcn_global_load_lds(                                       \
            GLB(&Wb[(size_t)(n0 + _r) * 1024 + _k0 + _c * 8]),                  \
            LDSP(_Bd + _it * 4096), 16, 0, 0);                                  \
    }                                                                           \
} while (0)

template <bool C_F32, bool SPLIT>
__global__ __launch_bounds__(512, 2) void gemm3_kernel(
    const unsigned short* __restrict__ Ab,
    const unsigned short* __restrict__ Wb,
    void* __restrict__ O0, void* __restrict__ O1, void* __restrict__ O2)
{
    __shared__ __align__(16) unsigned short As[3 * 256 * 64];   // 96 KB
    __shared__ __align__(16) unsigned short Bs[3 * 128 * 64];   // 48 KB

    const int tid  = threadIdx.x;
    const int lane = tid & 63;
    const int wave = tid >> 6;         // 0..7
    const int wm   = wave >> 2;        // 0..1  (M half)
    const int wn   = wave & 3;         // 0..3  (N quarter)
    const int lr   = lane & 15;
    const int lq   = lane >> 4;
    const int m0   = blockIdx.y * 256;
    const int n0   = blockIdx.x * 128;

    const int srow = tid >> 3;         // 0..63 within a 64-row staging stripe
    const int sc8  = tid & 7;          // 16B chunk within a row

    f32x4 acc[8][2];
    #pragma unroll
    for (int i = 0; i < 8; ++i)
        #pragma unroll
        for (int j = 0; j < 2; ++j)
            acc[i][j] = (f32x4){0.f, 0.f, 0.f, 0.f};

    // prologue: two tiles in flight
    STAGE3(0);
    STAGE3(1);

    for (int t = 0; t < 16; ++t) {
        // wait for tile t only (tile t+1's 6 loads stay in flight)
        if (t < 15) asm volatile("s_waitcnt vmcnt(6)" ::: "memory");
        else        asm volatile("s_waitcnt vmcnt(0)" ::: "memory");
        asm volatile("s_barrier" ::: "memory");
        // stage tile t+2 into the buffer compute(t-1) just finished with
        if (t + 2 < 16) STAGE3(t + 2);

        const unsigned short* Abuf = &As[(t % 3) * 16384];
        const unsigned short* Bbuf = &Bs[(t % 3) * 8192];
        #pragma unroll
        for (int ks = 0; ks < 2; ++ks) {
            bf16x8 af[8], bfr[2];
            #pragma unroll
            for (int i = 0; i < 8; ++i) {
                int row = wm * 128 + i * 16 + lr;
                af[i] = *reinterpret_cast<const bf16x8*>(
                    &Abuf[row * 64 + (((ks * 4 + lq) ^ (row & 7)) << 3)]);
            }
            #pragma unroll
            for (int j = 0; j < 2; ++j) {
                int row = wn * 32 + j * 16 + lr;
                bfr[j] = *reinterpret_cast<const bf16x8*>(
                    &Bbuf[row * 64 + (((ks * 4 + lq) ^ (row & 7)) << 3)]);
            }
            __builtin_amdgcn_s_setprio(1);
            #pragma unroll
            for (int i = 0; i < 8; ++i)
                #pragma unroll
                for (int j = 0; j < 2; ++j)
                    acc[i][j] = __builtin_amdgcn_mfma_f32_16x16x32_bf16(
                        af[i], bfr[j], acc[i][j], 0, 0, 0);
            __builtin_amdgcn_s_setprio(0);
        }
    }

    if (SPLIT) {
        const int tsel = n0 >> 10;               // uniform per block
        const int d0   = n0 & 1023;
        unsigned short* Out =
            (unsigned short*)(tsel == 0 ? O0 : tsel == 1 ? O1 : O2);
        #pragma unroll
        for (int i = 0; i < 8; ++i)
            #pragma unroll
            for (int j = 0; j < 2; ++j) {
                int col = d0 + wn * 32 + j * 16 + lr;
                #pragma unroll
                for (int r = 0; r < 4; ++r) {
                    int row = m0 + wm * 128 + i * 16 + lq * 4 + r;
                    Out[(size_t)row * 1024 + col] = f2bf(acc[i][j][r]);
                }
            }
    } else {
        float* Co = (float*)O0;
        #pragma unroll
        for (int i = 0; i < 8; ++i)
            #pragma unroll
            for (int j = 0; j < 2; ++j) {
                int col = n0 + wn * 32 + j * 16 + lr;
                #pragma unroll
                for (int r = 0; r < 4; ++r) {
                    int row = m0 + wm * 128 + i * 16 + lq * 4 + r;
                    Co[(size_t)row * 1024 + col] = acc[i][j][r];
                }
            }
    }
}

// ---------------------------------------------------------------------------
// Fallback GEMM (round-5 structure): C = A @ W^T, fp32 W staged via VGPRs.
// ---------------------------------------------------------------------------
#define GBM 128
#define GBN 128
#define GBK 64

template <bool A_F32, bool C_F32>
__global__ __launch_bounds__(256) void gemm_bt_kernel(
    const void* __restrict__ Av,
    const float* __restrict__ W,
    void* __restrict__ Cv,
    int M, int N, int K)
{
    __shared__ unsigned short As[GBM][GBK];
    __shared__ unsigned short Ws[GBN][GBK];

    const int tid  = threadIdx.x;
    const int lane = tid & 63;
    const int wave = tid >> 6;
    const int wm   = wave >> 1;
    const int wn   = wave & 1;
    const int lr   = lane & 15;
    const int lq   = lane >> 4;
    const int m0   = blockIdx.y * GBM;
    const int n0   = blockIdx.x * GBN;

    f32x4 acc[4][4];
    #pragma unroll
    for (int i = 0; i < 4; ++i)
        #pragma unroll
        for (int j = 0; j < 4; ++j)
            acc[i][j] = (f32x4){0.f, 0.f, 0.f, 0.f};

    for (int k0 = 0; k0 < K; k0 += GBK) {
        if (A_F32) {
            const float* A = (const float*)Av;
            #pragma unroll
            for (int i = 0; i < 8; ++i) {
                int idx = tid + i * 256;
                int row = idx >> 4;
                int c4  = idx & 15;
                float4 a = *reinterpret_cast<const float4*>(
                    &A[(size_t)(m0 + row) * K + k0 + c4 * 4]);
                ushort4 o;
                o.x = f2bf(a.x); o.y = f2bf(a.y);
                o.z = f2bf(a.z); o.w = f2bf(a.w);
                *reinterpret_cast<ushort4*>(&As[row][c4 * 4]) = o;
            }
        } else {
            const unsigned short* A = (const unsigned short*)Av;
            #pragma unroll
            for (int i = 0; i < 4; ++i) {
                int idx = tid + i * 256;
                int row = idx >> 3;
                int c8  = idx & 7;
                int4 v = *reinterpret_cast<const int4*>(
                    &A[(size_t)(m0 + row) * K + k0 + c8 * 8]);
                *reinterpret_cast<int4*>(&As[row][c8 * 8]) = v;
            }
        }
        #pragma unroll
        for (int i = 0; i < 8; ++i) {
            int idx = tid + i * 256;
            int row = idx >> 4;
            int c4  = idx & 15;
            float4 w = *reinterpret_cast<const float4*>(
                &W[(size_t)(n0 + row) * K + k0 + c4 * 4]);
            ushort4 o;
            o.x = f2bf(w.x); o.y = f2bf(w.y);
            o.z = f2bf(w.z); o.w = f2bf(w.w);
            *reinterpret_cast<ushort4*>(&Ws[row][c4 * 4]) = o;
        }
        __syncthreads();

        #pragma unroll
        for (int ks = 0; ks < 2; ++ks) {
            bf16x8 af[4], bfr[4];
            #pragma unroll
            for (int i = 0; i < 4; ++i)
                af[i] = *reinterpret_cast<const bf16x8*>(
                    &As[wm * 64 + i * 16 + lr][ks * 32 + lq * 8]);
            #pragma unroll
            for (int j = 0; j < 4; ++j)
                bfr[j] = *reinterpret_cast<const bf16x8*>(
                    &Ws[wn * 64 + j * 16 + lr][ks * 32 + lq * 8]);
            #pragma unroll
            for (int i = 0; i < 4; ++i)
                #pragma unroll
                for (int j = 0; j < 4; ++j)
                    acc[i][j] = __builtin_amdgcn_mfma_f32_16x16x32_bf16(
                        af[i], bfr[j], acc[i][j], 0, 0, 0);
        }
        __syncthreads();
    }

    #pragma unroll
    for (int i = 0; i < 4; ++i) {
        #pragma unroll
        for (int j = 0; j < 4; ++j) {
            int col = n0 + wn * 64 + j * 16 + lr;
            #pragma unroll
            for (int r = 0; r < 4; ++r) {
                int row = m0 + wm * 64 + i * 16 + lq * 4 + r;
                if (C_F32) {
                    ((float*)Cv)[(size_t)row * N + col] = acc[i][j][r];
                } else {
                    ((unsigned short*)Cv)[(size_t)row * N + col] = f2bf(acc[i][j][r]);
                }
            }
        }
    }
}

// ---------------------------------------------------------------------------
// Fixup v2 (unchanged): tail rows via W_ns, streaming coalesced reads.
// ---------------------------------------------------------------------------
__global__ __launch_bounds__(512) void fixup_kernel(
    const float* __restrict__ x,
    const float* __restrict__ Wq_ns,
    const float* __restrict__ Wk_ns,
    const float* __restrict__ Wv_ns,
    unsigned short* __restrict__ Q,
    unsigned short* __restrict__ Kb,
    unsigned short* __restrict__ V)
{
    const int bid   = blockIdx.x;
    const int wgt   = bid >> 6;
    const int chunk = bid & 63;
    const int proj  = wgt >> 3;
    const int n     = wgt & 7;
    const float* Wns =
        (proj == 0 ? Wq_ns : proj == 1 ? Wk_ns : Wv_ns) + (size_t)n * Dsz * Dsz;
    unsigned short* Out = (proj == 0 ? Q : proj == 1 ? Kb : V);
    const int l    = LSsz + n;
    const int b    = threadIdx.x >> 6;
    const int lane = threadIdx.x & 63;

    const float* xrow = x + ((size_t)b * Lsz + l) * Dsz;
    float4 xr[4];
    #pragma unroll
    for (int i = 0; i < 4; ++i)
        xr[i] = *reinterpret_cast<const float4*>(&xrow[lane * 4 + i * 256]);

    for (int er = 0; er < 16; ++er) {
        const int e = chunk * 16 + er;
        const float* wrow = Wns + (size_t)e * Dsz;
        float s = 0.f;
        #pragma unroll
        for (int i = 0; i < 4; ++i) {
            float4 wv = *reinterpret_cast<const float4*>(&wrow[lane * 4 + i * 256]);
            s += wv.x * xr[i].x + wv.y * xr[i].y
               + wv.z * xr[i].z + wv.w * xr[i].w;
        }
        #pragma unroll
        for (int off = 32; off > 0; off >>= 1) s += __shfl_xor(s, off, 64);
        if (lane == 0) Out[((size_t)b * Lsz + l) * Dsz + e] = f2bf(s);
    }
}

// ---------------------------------------------------------------------------
// MFMA flash attention, v3 (unchanged from round 2; verified 105.5 us).
// ---------------------------------------------------------------------------
__global__ __launch_bounds__(256, 4) void attn_mfma_kernel(
    const unsigned short* __restrict__ Q,
    const unsigned short* __restrict__ K,
    const unsigned short* __restrict__ V,
    unsigned short* __restrict__ O)
{
    __shared__ __align__(16) unsigned short Klds[2 * 4096];   // 64x64 dbuf, 16 KB
    __shared__ __align__(16) unsigned short Vtlds[4096];      // 64x64 transposed, 8 KB
    __shared__ __align__(16) unsigned short Plds[4][1024];    // per-wave P + O bounce, 8 KB

    const int tid  = threadIdx.x;
    const int lane = tid & 63;
    const int wave = tid >> 6;
    const int lr   = lane & 15;
    const int lq   = lane >> 4;

    const int id = blockIdx.x;
    const int qt = 15 - ((id >> 3) & 15);
    const int bh = ((id >> 7) << 3) | (id & 7);
    const int h  = bh & (Hh - 1);
    const int b  = bh >> 4;
    const int qw = qt * 64 + wave * 16;
    const int nkt = qt + 1;

    const size_t base = (size_t)b * Lsz * Dsz + (size_t)h * HDsz;

    bf16x8 qf[2];
    #pragma unroll
    for (int h2 = 0; h2 < 2; ++h2) {
        bf16x8 t = *reinterpret_cast<const bf16x8*>(
            &Q[base + (size_t)(qw + lr) * Dsz + h2 * 32 + lq * 8]);
        #pragma unroll
        for (int e = 0; e < 8; ++e) {
            float f = bf2f((unsigned short)t[e]) * 0.125f;
            t[e] = (short)f2bf(f);
        }
        qf[h2] = t;
    }

    f32x4 acc[4];
    #pragma unroll
    for (int jd = 0; jd < 4; ++jd) acc[jd] = (f32x4){0.f, 0.f, 0.f, 0.f};
    float m_i[4] = {-1e30f, -1e30f, -1e30f, -1e30f};
    float l_i[4] = {0.f, 0.f, 0.f, 0.f};

    const int krow0 = tid >> 3;
    const int kc8   = tid & 7;
    const int vd0   = (tid & 7) * 8;
    const int vk0   = (tid >> 3) * 2;

    unsigned short* Pw = &Plds[wave][0];
    int4 vq0, vq1;

    #pragma unroll
    for (int it = 0; it < 2; ++it) {
        int row  = it * 32 + krow0;
        int csrc = kc8 ^ (row & 7);
        const unsigned short* ga = &K[base + (size_t)row * Dsz + csrc * 8];
        __builtin_amdgcn_global_load_lds(GLB(ga),
            LDSP(&Klds[it * 2048 + wave * 512]), 16, 0, 0);
    }
    vq0 = *reinterpret_cast<const int4*>(&V[base + (size_t)(vk0 + 0) * Dsz + vd0]);
    vq1 = *reinterpret_cast<const int4*>(&V[base + (size_t)(vk0 + 1) * Dsz + vd0]);

    for (int kt = 0; kt < nkt; ++kt) {
        const int k0 = kt * 64;
        const int kb = (kt & 1) * 4096;

        __syncthreads();

        {
            union { int4 v; unsigned short u[8]; } a, c;
            a.v = vq0; c.v = vq1;
            const int kc  = vk0 >> 3;
            const int klo = vk0 & 7;
            #pragma unroll
            for (int d = 0; d < 8; ++d) {
                int dd  = vd0 + d;
                int idx = dd * 64 + (((kc ^ (dd & 7)) << 3) | klo);
                ushort2 p; p.x = a.u[d]; p.y = c.u[d];
                *reinterpret_cast<ushort2*>(&Vtlds[idx]) = p;
            }
        }
        __syncthreads();

        if (kt + 1 < nkt) {
            const int k0n = k0 + 64;
            #pragma unroll
            for (int it = 0; it < 2; ++it) {
                int row  = it * 32 + krow0;
                int csrc = kc8 ^ (row & 7);
                const unsigned short* ga =
                    &K[base + (size_t)(k0n + row) * Dsz + csrc * 8];
                __builtin_amdgcn_global_load_lds(GLB(ga),
                    LDSP(&Klds[(kb ^ 4096) + it * 2048 + wave * 512]), 16, 0, 0);
            }
            vq0 = *reinterpret_cast<const int4*>(
                &V[base + (size_t)(k0n + vk0 + 0) * Dsz + vd0]);
            vq1 = *reinterpret_cast<const int4*>(
                &V[base + (size_t)(k0n + vk0 + 1) * Dsz + vd0]);
        }

        f32x4 sv[4];
        #pragma unroll
        for (int jt = 0; jt < 4; ++jt) sv[jt] = (f32x4){0.f, 0.f, 0.f, 0.f};

        __builtin_amdgcn_s_setprio(1);
        #pragma unroll
        for (int h2 = 0; h2 < 2; ++h2) {
            const int cs = (((h2 << 2) | lq) ^ (lr & 7)) << 3;
            #pragma unroll
            for (int jt = 0; jt < 4; ++jt) {
                bf16x8 kf = *reinterpret_cast<const bf16x8*>(
                    &Klds[kb + (jt * 16 + lr) * 64 + cs]);
                sv[jt] = __builtin_amdgcn_mfma_f32_16x16x32_bf16(
                    qf[h2], kf, sv[jt], 0, 0, 0);
            }
        }
        __builtin_amdgcn_s_setprio(0);

        if (k0 + 63 > qw) {
            #pragma unroll
            for (int jt = 0; jt < 4; ++jt) {
                int kpos = k0 + jt * 16 + lr;
                #pragma unroll
                for (int r = 0; r < 4; ++r) {
                    int q = qw + lq * 4 + r;
                    if (kpos > q) sv[jt][r] = -1e30f;
                }
            }
        }

        float tm[4], al[4], rs[4];
        #pragma unroll
        for (int r = 0; r < 4; ++r)
            tm[r] = fmaxf(fmaxf(sv[0][r], sv[1][r]), fmaxf(sv[2][r], sv[3][r]));
        #pragma unroll
        for (int off = 1; off < 16; off <<= 1)
            #pragma unroll
            for (int r = 0; r < 4; ++r)
                tm[r] = fmaxf(tm[r], __shfl_xor(tm[r], off, 64));
        #pragma unroll
        for (int r = 0; r < 4; ++r) {
            float nm = fmaxf(m_i[r], tm[r]);
            al[r] = __expf(m_i[r] - nm);
            m_i[r] = nm;
        }
        #pragma unroll
        for (int jt = 0; jt < 4; ++jt)
            #pragma unroll
            for (int r = 0; r < 4; ++r)
                sv[jt][r] = __expf(sv[jt][r] - m_i[r]);
        #pragma unroll
        for (int r = 0; r < 4; ++r)
            rs[r] = (sv[0][r] + sv[1][r]) + (sv[2][r] + sv[3][r]);
        #pragma unroll
        for (int off = 1; off < 16; off <<= 1)
            #pragma unroll
            for (int r = 0; r < 4; ++r)
                rs[r] += __shfl_xor(rs[r], off, 64);
        #pragma unroll
        for (int r = 0; r < 4; ++r) l_i[r] = l_i[r] * al[r] + rs[r];
        #pragma unroll
        for (int jd = 0; jd < 4; ++jd)
            #pragma unroll
            for (int r = 0; r < 4; ++r)
                acc[jd][r] *= al[r];

        #pragma unroll
        for (int jt = 0; jt < 4; ++jt) {
            int kcol  = jt * 16 + lr;
            int chunk = kcol >> 3;
            int elem  = kcol & 7;
            #pragma unroll
            for (int r = 0; r < 4; ++r) {
                int qrow = lq * 4 + r;
                Pw[qrow * 64 + (((chunk ^ (qrow & 7)) << 3) | elem)] =
                    f2bf(sv[jt][r]);
            }
        }

        __builtin_amdgcn_s_setprio(1);
        #pragma unroll
        for (int h2 = 0; h2 < 2; ++h2) {
            const int cs = (((h2 << 2) | lq) ^ (lr & 7)) << 3;
            bf16x8 pf = *reinterpret_cast<const bf16x8*>(&Pw[lr * 64 + cs]);
            #pragma unroll
            for (int jd = 0; jd < 4; ++jd) {
                bf16x8 vf = *reinterpret_cast<const bf16x8*>(
                    &Vtlds[(jd * 16 + lr) * 64 + cs]);
                acc[jd] = __builtin_amdgcn_mfma_f32_16x16x32_bf16(
                    pf, vf, acc[jd], 0, 0, 0);
            }
        }
        __builtin_amdgcn_s_setprio(0);
    }

    float inv[4];
    #pragma unroll
    for (int r = 0; r < 4; ++r) inv[r] = 1.0f / l_i[r];
    #pragma unroll
    for (int jd = 0; jd < 4; ++jd) {
        #pragma unroll
        for (int r = 0; r < 4; ++r) {
            int qrow  = lq * 4 + r;
            int col   = jd * 16 + lr;
            int chunk = col >> 3;
            int elem  = col & 7;
            Pw[qrow * 64 + (((chunk ^ (qrow & 7)) << 3) | elem)] =
                f2bf(acc[jd][r] * inv[r]);
        }
    }
    #pragma unroll
    for (int it2 = 0; it2 < 2; ++it2) {
        int row = it2 * 8 + (lane >> 3);
        int c   = lane & 7;
        const int4 ov = *reinterpret_cast<const int4*>(
            &Pw[row * 64 + ((c ^ (row & 7)) << 3)]);
        *reinterpret_cast<int4*>(&O[base + (size_t)(qw + row) * Dsz + c * 8]) = ov;
    }
}

// ---------------------------------------------------------------------------
extern "C" void kernel_launch(void* const* d_in, const int* in_sizes, int n_in,
                              void* d_out, int out_size, void* d_ws, size_t ws_size,
                              hipStream_t stream)
{
    const float* x     = (const float*)d_in[0];
    const float* Wq_s  = (const float*)d_in[2];
    const float* Wk_s  = (const float*)d_in[3];
    const float* Wv_s  = (const float*)d_in[4];
    const float* Wq_ns = (const float*)d_in[5];
    const float* Wk_ns = (const float*)d_in[6];
    const float* Wv_ns = (const float*)d_in[7];
    const float* W_out = (const float*)d_in[8];
    float* out = (float*)d_out;

    const size_t nElem = (size_t)Bsz * Lsz * Dsz;            // 8388608
    unsigned short* Q    = (unsigned short*)d_ws;
    unsigned short* Kb   = Q + nElem;
    unsigned short* V    = Kb + nElem;
    unsigned short* Xb   = V + nElem;                        // xb, later O
    unsigned short* Wcat = Xb + nElem;
    unsigned short* Wob  = Wcat + 3 * 1048576;
    const size_t need = (4 * nElem + 4 * 1048576) * sizeof(unsigned short);

    if (ws_size >= need) {
        // ---- fast path: bf16 cast once, pipelined MFMA GEMMs ----
        cast_kernel<<<3072, 256, 0, stream>>>(x, Wq_s, Wk_s, Wv_s, W_out,
                                              Xb, Wcat, Wob);
        gemm3_kernel<false, true><<<dim3(24, 32), 512, 0, stream>>>(
            Xb, Wcat, Q, Kb, V);
        fixup_kernel<<<24 * 64, 512, 0, stream>>>(x, Wq_ns, Wk_ns, Wv_ns, Q, Kb, V);
        unsigned short* O = Xb;   // xb dead after qkv gemm; reuse for attn out
        attn_mfma_kernel<<<Bsz * Hh * (Lsz / 64), 256, 0, stream>>>(Q, Kb, V, O);
        gemm3_kernel<true, false><<<dim3(8, 32), 512, 0, stream>>>(
            O, Wob, out, nullptr, nullptr);
    } else {
        // ---- fallback (round-5 path), needs only 4*nElem*2 bytes ----
        unsigned short* O = Xb;
        dim3 ggrid(Dsz / GBN, (Bsz * Lsz) / GBM);
        gemm_bt_kernel<true, false><<<ggrid, 256, 0, stream>>>(x, Wq_s, Q,  Bsz * Lsz, Dsz, Dsz);
        gemm_bt_kernel<true, false><<<ggrid, 256, 0, stream>>>(x, Wk_s, Kb, Bsz * Lsz, Dsz, Dsz);
        gemm_bt_kernel<true, false><<<ggrid, 256, 0, stream>>>(x, Wv_s, V,  Bsz * Lsz, Dsz, Dsz);
        fixup_kernel<<<24 * 64, 512, 0, stream>>>(x, Wq_ns, Wk_ns, Wv_ns, Q, Kb, V);
        attn_mfma_kernel<<<Bsz * Hh * (Lsz / 64), 256, 0, stream>>>(Q, Kb, V, O);
        gemm_bt_kernel<false, true><<<ggrid, 256, 0, stream>>>(O, W_out, out, Bsz * Lsz, Dsz, Dsz);
    }
}

// Round 4
// 369.765 us; speedup vs baseline: 1.3890x; 1.0494x over previous
//
#include <hip/hip_runtime.h>

// Problem constants (B,L,D,H fixed from reference)
#define Bsz  8
#define Lsz  1024
#define Dsz  1024
#define Hh   16
#define HDsz 64
#define NSsz 8
#define LSsz 1016

typedef short  bf16x8 __attribute__((ext_vector_type(8)));   // 8 bf16 (4 VGPRs)
typedef float  f32x4  __attribute__((ext_vector_type(4)));

#define GLB(p) ((const __attribute__((address_space(1))) unsigned int*)(p))
#define LDSP(p) ((__attribute__((address_space(3))) unsigned int*)(p))

__device__ __forceinline__ float bf2f(unsigned short u) {
    union { unsigned int i; float f; } v; v.i = ((unsigned int)u) << 16; return v.f;
}
__device__ __forceinline__ unsigned short f2bf(float f) {
    union { float f; unsigned int i; } v; v.f = f;
    unsigned int x = v.i;
    return (unsigned short)((x + 0x7FFFu + ((x >> 16) & 1u)) >> 16);
}
__device__ __forceinline__ void gload(const unsigned short* g, unsigned short* l) {
    __builtin_amdgcn_global_load_lds(GLB(g), LDSP(l), 16, 0, 0);
}

// ---------------------------------------------------------------------------
// Cast kernel: x (fp32) -> xb (bf16); Wq_s|Wk_s|Wv_s -> Wcat; W_out -> Wob.
// ---------------------------------------------------------------------------
__global__ __launch_bounds__(256) void cast_kernel(
    const float* __restrict__ x,
    const float* __restrict__ wq, const float* __restrict__ wk,
    const float* __restrict__ wv, const float* __restrict__ wo,
    unsigned short* __restrict__ xb,
    unsigned short* __restrict__ wcat,
    unsigned short* __restrict__ wob)
{
    const size_t NX = 2097152;   // float4s in x (8388608 elems)
    const size_t NW = 262144;    // float4s per DxD weight
    size_t i = (size_t)blockIdx.x * 256 + threadIdx.x;
    const size_t stride = (size_t)gridDim.x * 256;
    const size_t total = NX + 4 * NW;
    for (; i < total; i += stride) {
        const float* src; unsigned short* dst; size_t off;
        if (i < NX)               { src = x;  dst = xb;             off = i; }
        else if (i < NX + NW)     { src = wq; dst = wcat;           off = i - NX; }
        else if (i < NX + 2 * NW) { src = wk; dst = wcat + 1048576; off = i - NX - NW; }
        else if (i < NX + 3 * NW) { src = wv; dst = wcat + 2097152; off = i - NX - 2 * NW; }
        else                      { src = wo; dst = wob;            off = i - NX - 3 * NW; }
        float4 v = reinterpret_cast<const float4*>(src)[off];
        ushort4 o;
        o.x = f2bf(v.x); o.y = f2bf(v.y); o.z = f2bf(v.z); o.w = f2bf(v.w);
        reinterpret_cast<ushort4*>(dst)[off] = o;
    }
}

// ---------------------------------------------------------------------------
// Phase-locked pipelined GEMM (T3+T4+T5): C = A[M x 1024] @ W[N x 1024]^T.
// BM=256, BN=128, BK=64; 8 waves (2M x 4N), 512 threads; per-wave 128x32.
// Triple-buffered LDS (144 KB), 2-tile stage lag.
// Per K-tile: TWO barrier-bracketed phases (one per ks):
//   { ds_read 10x b128 (this ks) ; issue 3 stage loads (tile t+2, phase ks) ;
//     [at ks==1: s_waitcnt vmcnt(6) — tile boundary, never 0 until tail] ;
//     s_barrier ; lgkmcnt(0)+sched_barrier(0) ; setprio(1) 16x MFMA setprio(0);
//     s_barrier }
// Raw s_barrier only (no __syncthreads: must not drain vmcnt).
// SPLIT: output cols [0,1024)->O0, [1024,2048)->O1, [2048,3072)->O2 (bf16);
// else single f32 output O0.
// ---------------------------------------------------------------------------
template <bool C_F32, bool SPLIT>
__global__ __launch_bounds__(512, 2) void gemm8_kernel(
    const unsigned short* __restrict__ Ab,
    const unsigned short* __restrict__ Wb,
    void* __restrict__ O0, void* __restrict__ O1, void* __restrict__ O2)
{
    __shared__ __align__(16) unsigned short As[3 * 16384];   // 3 x 256x64, 96 KB
    __shared__ __align__(16) unsigned short Bs[3 * 8192];    // 3 x 128x64, 48 KB

    const int tid  = threadIdx.x;
    const int lane = tid & 63;
    const int wave = tid >> 6;         // 0..7
    const int wm   = wave >> 2;        // 0..1  (M half)
    const int wn   = wave & 3;         // 0..3  (N quarter)
    const int lr   = lane & 15;
    const int lq   = lane >> 4;
    const int m0   = blockIdx.y * 256;
    const int n0   = blockIdx.x * 128;

    const int srow = tid >> 3;         // 0..63 staging row within a 64-row unit
    const int sc8  = tid & 7;          // 16B chunk within a row

    // stage one phase (3 x 8KB units) of K-tile tt into buffer tt%3.
    // LDS dest linear; global source chunk pre-swizzled (c8 stores c8^(row&7)).
    auto stage_ph = [&](int tt, int ph) {
        const int k0 = tt * 64;
        unsigned short* Abase = &As[(tt % 3) * 16384];
        unsigned short* Bbase = &Bs[(tt % 3) * 8192];
        if (ph == 0) {
            #pragma unroll
            for (int u = 0; u < 2; ++u) {
                int r = u * 64 + srow;
                int c = sc8 ^ (r & 7);
                gload(&Ab[(size_t)(m0 + r) * 1024 + k0 + c * 8],
                      &Abase[u * 4096 + wave * 512]);
            }
            int r = srow, c = sc8 ^ (r & 7);
            gload(&Wb[(size_t)(n0 + r) * 1024 + k0 + c * 8],
                  &Bbase[wave * 512]);
        } else {
            #pragma unroll
            for (int u = 2; u < 4; ++u) {
                int r = u * 64 + srow;
                int c = sc8 ^ (r & 7);
                gload(&Ab[(size_t)(m0 + r) * 1024 + k0 + c * 8],
                      &Abase[u * 4096 + wave * 512]);
            }
            int r = 64 + srow, c = sc8 ^ (r & 7);
            gload(&Wb[(size_t)(n0 + r) * 1024 + k0 + c * 8],
                  &Bbase[4096 + wave * 512]);
        }
    };

    f32x4 acc[8][2];
    #pragma unroll
    for (int i = 0; i < 8; ++i)
        #pragma unroll
        for (int j = 0; j < 2; ++j)
            acc[i][j] = (f32x4){0.f, 0.f, 0.f, 0.f};

    // prologue: tiles 0 and 1 fully staged (12 loads/thread in flight)
    stage_ph(0, 0); stage_ph(0, 1);
    stage_ph(1, 0); stage_ph(1, 1);
    asm volatile("s_waitcnt vmcnt(6)" ::: "memory");   // tile 0 landed
    __builtin_amdgcn_s_barrier();

    for (int t = 0; t < 16; ++t) {
        const unsigned short* Abuf = &As[(t % 3) * 16384];
        const unsigned short* Bbuf = &Bs[(t % 3) * 8192];
        #pragma unroll
        for (int ks = 0; ks < 2; ++ks) {
            // ds_read this phase's fragments (latency hides under barrier wait)
            bf16x8 af[8], bfr[2];
            #pragma unroll
            for (int i = 0; i < 8; ++i) {
                int row = wm * 128 + i * 16 + lr;
                af[i] = *reinterpret_cast<const bf16x8*>(
                    &Abuf[row * 64 + (((ks * 4 + lq) ^ (row & 7)) << 3)]);
            }
            #pragma unroll
            for (int j = 0; j < 2; ++j) {
                int row = wn * 32 + j * 16 + lr;
                bfr[j] = *reinterpret_cast<const bf16x8*>(
                    &Bbuf[row * 64 + (((ks * 4 + lq) ^ (row & 7)) << 3)]);
            }
            // stage phase ks of tile t+2 into the buffer freed at end of t-1
            if (t + 2 < 16) stage_ph(t + 2, ks);
            // tile-boundary wait: keep tile t+2's 6 loads in flight
            if (ks == 1) {
                if (t + 2 < 16)
                    asm volatile("s_waitcnt vmcnt(6)" ::: "memory");
                else if (t + 1 < 16)
                    asm volatile("s_waitcnt vmcnt(0)" ::: "memory");
            }
            __builtin_amdgcn_s_barrier();
            asm volatile("s_waitcnt lgkmcnt(0)" ::: "memory");
            __builtin_amdgcn_sched_barrier(0);
            __builtin_amdgcn_s_setprio(1);
            #pragma unroll
            for (int i = 0; i < 8; ++i)
                #pragma unroll
                for (int j = 0; j < 2; ++j)
                    acc[i][j] = __builtin_amdgcn_mfma_f32_16x16x32_bf16(
                        af[i], bfr[j], acc[i][j], 0, 0, 0);
            __builtin_amdgcn_s_setprio(0);
            __builtin_amdgcn_s_barrier();
        }
    }

    if (SPLIT) {
        const int tsel = n0 >> 10;               // uniform per block
        const int d0   = n0 & 1023;
        unsigned short* Out =
            (unsigned short*)(tsel == 0 ? O0 : tsel == 1 ? O1 : O2);
        #pragma unroll
        for (int i = 0; i < 8; ++i)
            #pragma unroll
            for (int j = 0; j < 2; ++j) {
                int col = d0 + wn * 32 + j * 16 + lr;
                #pragma unroll
                for (int r = 0; r < 4; ++r) {
                    int row = m0 + wm * 128 + i * 16 + lq * 4 + r;
                    Out[(size_t)row * 1024 + col] = f2bf(acc[i][j][r]);
                }
            }
    } else {
        float* Co = (float*)O0;
        #pragma unroll
        for (int i = 0; i < 8; ++i)
            #pragma unroll
            for (int j = 0; j < 2; ++j) {
                int col = n0 + wn * 32 + j * 16 + lr;
                #pragma unroll
                for (int r = 0; r < 4; ++r) {
                    int row = m0 + wm * 128 + i * 16 + lq * 4 + r;
                    Co[(size_t)row * 1024 + col] = acc[i][j][r];
                }
            }
    }
}

// ---------------------------------------------------------------------------
// Fallback GEMM (round-5 structure): C = A @ W^T, fp32 W staged via VGPRs.
// ---------------------------------------------------------------------------
#define GBM 128
#define GBN 128
#define GBK 64

template <bool A_F32, bool C_F32>
__global__ __launch_bounds__(256) void gemm_bt_kernel(
    const void* __restrict__ Av,
    const float* __restrict__ W,
    void* __restrict__ Cv,
    int M, int N, int K)
{
    __shared__ unsigned short As[GBM][GBK];
    __shared__ unsigned short Ws[GBN][GBK];

    const int tid  = threadIdx.x;
    const int lane = tid & 63;
    const int wave = tid >> 6;
    const int wm   = wave >> 1;
    const int wn   = wave & 1;
    const int lr   = lane & 15;
    const int lq   = lane >> 4;
    const int m0   = blockIdx.y * GBM;
    const int n0   = blockIdx.x * GBN;

    f32x4 acc[4][4];
    #pragma unroll
    for (int i = 0; i < 4; ++i)
        #pragma unroll
        for (int j = 0; j < 4; ++j)
            acc[i][j] = (f32x4){0.f, 0.f, 0.f, 0.f};

    for (int k0 = 0; k0 < K; k0 += GBK) {
        if (A_F32) {
            const float* A = (const float*)Av;
            #pragma unroll
            for (int i = 0; i < 8; ++i) {
                int idx = tid + i * 256;
                int row = idx >> 4;
                int c4  = idx & 15;
                float4 a = *reinterpret_cast<const float4*>(
                    &A[(size_t)(m0 + row) * K + k0 + c4 * 4]);
                ushort4 o;
                o.x = f2bf(a.x); o.y = f2bf(a.y);
                o.z = f2bf(a.z); o.w = f2bf(a.w);
                *reinterpret_cast<ushort4*>(&As[row][c4 * 4]) = o;
            }
        } else {
            const unsigned short* A = (const unsigned short*)Av;
            #pragma unroll
            for (int i = 0; i < 4; ++i) {
                int idx = tid + i * 256;
                int row = idx >> 3;
                int c8  = idx & 7;
                int4 v = *reinterpret_cast<const int4*>(
                    &A[(size_t)(m0 + row) * K + k0 + c8 * 8]);
                *reinterpret_cast<int4*>(&As[row][c8 * 8]) = v;
            }
        }
        #pragma unroll
        for (int i = 0; i < 8; ++i) {
            int idx = tid + i * 256;
            int row = idx >> 4;
            int c4  = idx & 15;
            float4 w = *reinterpret_cast<const float4*>(
                &W[(size_t)(n0 + row) * K + k0 + c4 * 4]);
            ushort4 o;
            o.x = f2bf(w.x); o.y = f2bf(w.y);
            o.z = f2bf(w.z); o.w = f2bf(w.w);
            *reinterpret_cast<ushort4*>(&Ws[row][c4 * 4]) = o;
        }
        __syncthreads();

        #pragma unroll
        for (int ks = 0; ks < 2; ++ks) {
            bf16x8 af[4], bfr[4];
            #pragma unroll
            for (int i = 0; i < 4; ++i)
                af[i] = *reinterpret_cast<const bf16x8*>(
                    &As[wm * 64 + i * 16 + lr][ks * 32 + lq * 8]);
            #pragma unroll
            for (int j = 0; j < 4; ++j)
                bfr[j] = *reinterpret_cast<const bf16x8*>(
                    &Ws[wn * 64 + j * 16 + lr][ks * 32 + lq * 8]);
            #pragma unroll
            for (int i = 0; i < 4; ++i)
                #pragma unroll
                for (int j = 0; j < 4; ++j)
                    acc[i][j] = __builtin_amdgcn_mfma_f32_16x16x32_bf16(
                        af[i], bfr[j], acc[i][j], 0, 0, 0);
        }
        __syncthreads();
    }

    #pragma unroll
    for (int i = 0; i < 4; ++i) {
        #pragma unroll
        for (int j = 0; j < 4; ++j) {
            int col = n0 + wn * 64 + j * 16 + lr;
            #pragma unroll
            for (int r = 0; r < 4; ++r) {
                int row = m0 + wm * 64 + i * 16 + lq * 4 + r;
                if (C_F32) {
                    ((float*)Cv)[(size_t)row * N + col] = acc[i][j][r];
                } else {
                    ((unsigned short*)Cv)[(size_t)row * N + col] = f2bf(acc[i][j][r]);
                }
            }
        }
    }
}

// ---------------------------------------------------------------------------
// Fixup v2 (unchanged): tail rows via W_ns, streaming coalesced reads.
// ---------------------------------------------------------------------------
__global__ __launch_bounds__(512) void fixup_kernel(
    const float* __restrict__ x,
    const float* __restrict__ Wq_ns,
    const float* __restrict__ Wk_ns,
    const float* __restrict__ Wv_ns,
    unsigned short* __restrict__ Q,
    unsigned short* __restrict__ Kb,
    unsigned short* __restrict__ V)
{
    const int bid   = blockIdx.x;
    const int wgt   = bid >> 6;
    const int chunk = bid & 63;
    const int proj  = wgt >> 3;
    const int n     = wgt & 7;
    const float* Wns =
        (proj == 0 ? Wq_ns : proj == 1 ? Wk_ns : Wv_ns) + (size_t)n * Dsz * Dsz;
    unsigned short* Out = (proj == 0 ? Q : proj == 1 ? Kb : V);
    const int l    = LSsz + n;
    const int b    = threadIdx.x >> 6;
    const int lane = threadIdx.x & 63;

    const float* xrow = x + ((size_t)b * Lsz + l) * Dsz;
    float4 xr[4];
    #pragma unroll
    for (int i = 0; i < 4; ++i)
        xr[i] = *reinterpret_cast<const float4*>(&xrow[lane * 4 + i * 256]);

    for (int er = 0; er < 16; ++er) {
        const int e = chunk * 16 + er;
        const float* wrow = Wns + (size_t)e * Dsz;
        float s = 0.f;
        #pragma unroll
        for (int i = 0; i < 4; ++i) {
            float4 wv = *reinterpret_cast<const float4*>(&wrow[lane * 4 + i * 256]);
            s += wv.x * xr[i].x + wv.y * xr[i].y
               + wv.z * xr[i].z + wv.w * xr[i].w;
        }
        #pragma unroll
        for (int off = 32; off > 0; off >>= 1) s += __shfl_xor(s, off, 64);
        if (lane == 0) Out[((size_t)b * Lsz + l) * Dsz + e] = f2bf(s);
    }
}

// ---------------------------------------------------------------------------
// MFMA flash attention, v3 (unchanged; verified 105.5 us).
// ---------------------------------------------------------------------------
__global__ __launch_bounds__(256, 4) void attn_mfma_kernel(
    const unsigned short* __restrict__ Q,
    const unsigned short* __restrict__ K,
    const unsigned short* __restrict__ V,
    unsigned short* __restrict__ O)
{
    __shared__ __align__(16) unsigned short Klds[2 * 4096];   // 64x64 dbuf, 16 KB
    __shared__ __align__(16) unsigned short Vtlds[4096];      // 64x64 transposed, 8 KB
    __shared__ __align__(16) unsigned short Plds[4][1024];    // per-wave P + O bounce, 8 KB

    const int tid  = threadIdx.x;
    const int lane = tid & 63;
    const int wave = tid >> 6;
    const int lr   = lane & 15;
    const int lq   = lane >> 4;

    const int id = blockIdx.x;
    const int qt = 15 - ((id >> 3) & 15);
    const int bh = ((id >> 7) << 3) | (id & 7);
    const int h  = bh & (Hh - 1);
    const int b  = bh >> 4;
    const int qw = qt * 64 + wave * 16;
    const int nkt = qt + 1;

    const size_t base = (size_t)b * Lsz * Dsz + (size_t)h * HDsz;

    bf16x8 qf[2];
    #pragma unroll
    for (int h2 = 0; h2 < 2; ++h2) {
        bf16x8 t = *reinterpret_cast<const bf16x8*>(
            &Q[base + (size_t)(qw + lr) * Dsz + h2 * 32 + lq * 8]);
        #pragma unroll
        for (int e = 0; e < 8; ++e) {
            float f = bf2f((unsigned short)t[e]) * 0.125f;
            t[e] = (short)f2bf(f);
        }
        qf[h2] = t;
    }

    f32x4 acc[4];
    #pragma unroll
    for (int jd = 0; jd < 4; ++jd) acc[jd] = (f32x4){0.f, 0.f, 0.f, 0.f};
    float m_i[4] = {-1e30f, -1e30f, -1e30f, -1e30f};
    float l_i[4] = {0.f, 0.f, 0.f, 0.f};

    const int krow0 = tid >> 3;
    const int kc8   = tid & 7;
    const int vd0   = (tid & 7) * 8;
    const int vk0   = (tid >> 3) * 2;

    unsigned short* Pw = &Plds[wave][0];
    int4 vq0, vq1;

    #pragma unroll
    for (int it = 0; it < 2; ++it) {
        int row  = it * 32 + krow0;
        int csrc = kc8 ^ (row & 7);
        const unsigned short* ga = &K[base + (size_t)row * Dsz + csrc * 8];
        __builtin_amdgcn_global_load_lds(GLB(ga),
            LDSP(&Klds[it * 2048 + wave * 512]), 16, 0, 0);
    }
    vq0 = *reinterpret_cast<const int4*>(&V[base + (size_t)(vk0 + 0) * Dsz + vd0]);
    vq1 = *reinterpret_cast<const int4*>(&V[base + (size_t)(vk0 + 1) * Dsz + vd0]);

    for (int kt = 0; kt < nkt; ++kt) {
        const int k0 = kt * 64;
        const int kb = (kt & 1) * 4096;

        __syncthreads();

        {
            union { int4 v; unsigned short u[8]; } a, c;
            a.v = vq0; c.v = vq1;
            const int kc  = vk0 >> 3;
            const int klo = vk0 & 7;
            #pragma unroll
            for (int d = 0; d < 8; ++d) {
                int dd  = vd0 + d;
                int idx = dd * 64 + (((kc ^ (dd & 7)) << 3) | klo);
                ushort2 p; p.x = a.u[d]; p.y = c.u[d];
                *reinterpret_cast<ushort2*>(&Vtlds[idx]) = p;
            }
        }
        __syncthreads();

        if (kt + 1 < nkt) {
            const int k0n = k0 + 64;
            #pragma unroll
            for (int it = 0; it < 2; ++it) {
                int row  = it * 32 + krow0;
                int csrc = kc8 ^ (row & 7);
                const unsigned short* ga =
                    &K[base + (size_t)(k0n + row) * Dsz + csrc * 8];
                __builtin_amdgcn_global_load_lds(GLB(ga),
                    LDSP(&Klds[(kb ^ 4096) + it * 2048 + wave * 512]), 16, 0, 0);
            }
            vq0 = *reinterpret_cast<const int4*>(
                &V[base + (size_t)(k0n + vk0 + 0) * Dsz + vd0]);
            vq1 = *reinterpret_cast<const int4*>(
                &V[base + (size_t)(k0n + vk0 + 1) * Dsz + vd0]);
        }

        f32x4 sv[4];
        #pragma unroll
        for (int jt = 0; jt < 4; ++jt) sv[jt] = (f32x4){0.f, 0.f, 0.f, 0.f};

        __builtin_amdgcn_s_setprio(1);
        #pragma unroll
        for (int h2 = 0; h2 < 2; ++h2) {
            const int cs = (((h2 << 2) | lq) ^ (lr & 7)) << 3;
            #pragma unroll
            for (int jt = 0; jt < 4; ++jt) {
                bf16x8 kf = *reinterpret_cast<const bf16x8*>(
                    &Klds[kb + (jt * 16 + lr) * 64 + cs]);
                sv[jt] = __builtin_amdgcn_mfma_f32_16x16x32_bf16(
                    qf[h2], kf, sv[jt], 0, 0, 0);
            }
        }
        __builtin_amdgcn_s_setprio(0);

        if (k0 + 63 > qw) {
            #pragma unroll
            for (int jt = 0; jt < 4; ++jt) {
                int kpos = k0 + jt * 16 + lr;
                #pragma unroll
                for (int r = 0; r < 4; ++r) {
                    int q = qw + lq * 4 + r;
                    if (kpos > q) sv[jt][r] = -1e30f;
                }
            }
        }

        float tm[4], al[4], rs[4];
        #pragma unroll
        for (int r = 0; r < 4; ++r)
            tm[r] = fmaxf(fmaxf(sv[0][r], sv[1][r]), fmaxf(sv[2][r], sv[3][r]));
        #pragma unroll
        for (int off = 1; off < 16; off <<= 1)
            #pragma unroll
            for (int r = 0; r < 4; ++r)
                tm[r] = fmaxf(tm[r], __shfl_xor(tm[r], off, 64));
        #pragma unroll
        for (int r = 0; r < 4; ++r) {
            float nm = fmaxf(m_i[r], tm[r]);
            al[r] = __expf(m_i[r] - nm);
            m_i[r] = nm;
        }
        #pragma unroll
        for (int jt = 0; jt < 4; ++jt)
            #pragma unroll
            for (int r = 0; r < 4; ++r)
                sv[jt][r] = __expf(sv[jt][r] - m_i[r]);
        #pragma unroll
        for (int r = 0; r < 4; ++r)
            rs[r] = (sv[0][r] + sv[1][r]) + (sv[2][r] + sv[3][r]);
        #pragma unroll
        for (int off = 1; off < 16; off <<= 1)
            #pragma unroll
            for (int r = 0; r < 4; ++r)
                rs[r] += __shfl_xor(rs[r], off, 64);
        #pragma unroll
        for (int r = 0; r < 4; ++r) l_i[r] = l_i[r] * al[r] + rs[r];
        #pragma unroll
        for (int jd = 0; jd < 4; ++jd)
            #pragma unroll
            for (int r = 0; r < 4; ++r)
                acc[jd][r] *= al[r];

        #pragma unroll
        for (int jt = 0; jt < 4; ++jt) {
            int kcol  = jt * 16 + lr;
            int chunk = kcol >> 3;
            int elem  = kcol & 7;
            #pragma unroll
            for (int r = 0; r < 4; ++r) {
                int qrow = lq * 4 + r;
                Pw[qrow * 64 + (((chunk ^ (qrow & 7)) << 3) | elem)] =
                    f2bf(sv[jt][r]);
            }
        }

        __builtin_amdgcn_s_setprio(1);
        #pragma unroll
        for (int h2 = 0; h2 < 2; ++h2) {
            const int cs = (((h2 << 2) | lq) ^ (lr & 7)) << 3;
            bf16x8 pf = *reinterpret_cast<const bf16x8*>(&Pw[lr * 64 + cs]);
            #pragma unroll
            for (int jd = 0; jd < 4; ++jd) {
                bf16x8 vf = *reinterpret_cast<const bf16x8*>(
                    &Vtlds[(jd * 16 + lr) * 64 + cs]);
                acc[jd] = __builtin_amdgcn_mfma_f32_16x16x32_bf16(
                    pf, vf, acc[jd], 0, 0, 0);
            }
        }
        __builtin_amdgcn_s_setprio(0);
    }

    float inv[4];
    #pragma unroll
    for (int r = 0; r < 4; ++r) inv[r] = 1.0f / l_i[r];
    #pragma unroll
    for (int jd = 0; jd < 4; ++jd) {
        #pragma unroll
        for (int r = 0; r < 4; ++r) {
            int qrow  = lq * 4 + r;
            int col   = jd * 16 + lr;
            int chunk = col >> 3;
            int elem  = col & 7;
            Pw[qrow * 64 + (((chunk ^ (qrow & 7)) << 3) | elem)] =
                f2bf(acc[jd][r] * inv[r]);
        }
    }
    #pragma unroll
    for (int it2 = 0; it2 < 2; ++it2) {
        int row = it2 * 8 + (lane >> 3);
        int c   = lane & 7;
        const int4 ov = *reinterpret_cast<const int4*>(
            &Pw[row * 64 + ((c ^ (row & 7)) << 3)]);
        *reinterpret_cast<int4*>(&O[base + (size_t)(qw + row) * Dsz + c * 8]) = ov;
    }
}

// ---------------------------------------------------------------------------
extern "C" void kernel_launch(void* const* d_in, const int* in_sizes, int n_in,
                              void* d_out, int out_size, void* d_ws, size_t ws_size,
                              hipStream_t stream)
{
    const float* x     = (const float*)d_in[0];
    const float* Wq_s  = (const float*)d_in[2];
    const float* Wk_s  = (const float*)d_in[3];
    const float* Wv_s  = (const float*)d_in[4];
    const float* Wq_ns = (const float*)d_in[5];
    const float* Wk_ns = (const float*)d_in[6];
    const float* Wv_ns = (const float*)d_in[7];
    const float* W_out = (const float*)d_in[8];
    float* out = (float*)d_out;

    const size_t nElem = (size_t)Bsz * Lsz * Dsz;            // 8388608
    unsigned short* Q    = (unsigned short*)d_ws;
    unsigned short* Kb   = Q + nElem;
    unsigned short* V    = Kb + nElem;
    unsigned short* Xb   = V + nElem;                        // xb, later O
    unsigned short* Wcat = Xb + nElem;
    unsigned short* Wob  = Wcat + 3 * 1048576;
    const size_t need = (4 * nElem + 4 * 1048576) * sizeof(unsigned short);

    if (ws_size >= need) {
        // ---- fast path: bf16 cast once, phase-locked MFMA GEMMs ----
        cast_kernel<<<3072, 256, 0, stream>>>(x, Wq_s, Wk_s, Wv_s, W_out,
                                              Xb, Wcat, Wob);
        gemm8_kernel<false, true><<<dim3(24, 32), 512, 0, stream>>>(
            Xb, Wcat, Q, Kb, V);
        fixup_kernel<<<24 * 64, 512, 0, stream>>>(x, Wq_ns, Wk_ns, Wv_ns, Q, Kb, V);
        unsigned short* O = Xb;   // xb dead after qkv gemm; reuse for attn out
        attn_mfma_kernel<<<Bsz * Hh * (Lsz / 64), 256, 0, stream>>>(Q, Kb, V, O);
        gemm8_kernel<true, false><<<dim3(8, 32), 512, 0, stream>>>(
            O, Wob, out, nullptr, nullptr);
    } else {
        // ---- fallback (round-5 path), needs only 4*nElem*2 bytes ----
        unsigned short* O = Xb;
        dim3 ggrid(Dsz / GBN, (Bsz * Lsz) / GBM);
        gemm_bt_kernel<true, false><<<ggrid, 256, 0, stream>>>(x, Wq_s, Q,  Bsz * Lsz, Dsz, Dsz);
        gemm_bt_kernel<true, false><<<ggrid, 256, 0, stream>>>(x, Wk_s, Kb, Bsz * Lsz, Dsz, Dsz);
        gemm_bt_kernel<true, false><<<ggrid, 256, 0, stream>>>(x, Wv_s, V,  Bsz * Lsz, Dsz, Dsz);
        fixup_kernel<<<24 * 64, 512, 0, stream>>>(x, Wq_ns, Wk_ns, Wv_ns, Q, Kb, V);
        attn_mfma_kernel<<<Bsz * Hh * (Lsz / 64), 256, 0, stream>>>(Q, Kb, V, O);
        gemm_bt_kernel<false, true><<<ggrid, 256, 0, stream>>>(O, W_out, out, Bsz * Lsz, Dsz, Dsz);
    }
}

// Round 5
// 366.597 us; speedup vs baseline: 1.4010x; 1.0086x over previous
//
#include <hip/hip_runtime.h>

// Problem constants (B,L,D,H fixed from reference)
#define Bsz  8
#define Lsz  1024
#define Dsz  1024
#define Hh   16
#define HDsz 64
#define NSsz 8
#define LSsz 1016

typedef short  bf16x8 __attribute__((ext_vector_type(8)));   // 8 bf16 (4 VGPRs)
typedef float  f32x4  __attribute__((ext_vector_type(4)));

#define GLB(p) ((const __attribute__((address_space(1))) unsigned int*)(p))
#define LDSP(p) ((__attribute__((address_space(3))) unsigned int*)(p))

__device__ __forceinline__ float bf2f(unsigned short u) {
    union { unsigned int i; float f; } v; v.i = ((unsigned int)u) << 16; return v.f;
}
__device__ __forceinline__ unsigned short f2bf(float f) {
    union { float f; unsigned int i; } v; v.f = f;
    unsigned int x = v.i;
    return (unsigned short)((x + 0x7FFFu + ((x >> 16) & 1u)) >> 16);
}
__device__ __forceinline__ void gload(const unsigned short* g, unsigned short* l) {
    __builtin_amdgcn_global_load_lds(GLB(g), LDSP(l), 16, 0, 0);
}

// ---------------------------------------------------------------------------
// Cast kernel: x (fp32) -> xb (bf16); Wq_s|Wk_s|Wv_s -> Wcat; W_out -> Wob.
// ---------------------------------------------------------------------------
__global__ __launch_bounds__(256) void cast_kernel(
    const float* __restrict__ x,
    const float* __restrict__ wq, const float* __restrict__ wk,
    const float* __restrict__ wv, const float* __restrict__ wo,
    unsigned short* __restrict__ xb,
    unsigned short* __restrict__ wcat,
    unsigned short* __restrict__ wob)
{
    const size_t NX = 2097152;   // float4s in x (8388608 elems)
    const size_t NW = 262144;    // float4s per DxD weight
    size_t i = (size_t)blockIdx.x * 256 + threadIdx.x;
    const size_t stride = (size_t)gridDim.x * 256;
    const size_t total = NX + 4 * NW;
    for (; i < total; i += stride) {
        const float* src; unsigned short* dst; size_t off;
        if (i < NX)               { src = x;  dst = xb;             off = i; }
        else if (i < NX + NW)     { src = wq; dst = wcat;           off = i - NX; }
        else if (i < NX + 2 * NW) { src = wk; dst = wcat + 1048576; off = i - NX - NW; }
        else if (i < NX + 3 * NW) { src = wv; dst = wcat + 2097152; off = i - NX - 2 * NW; }
        else                      { src = wo; dst = wob;            off = i - NX - 3 * NW; }
        float4 v = reinterpret_cast<const float4*>(src)[off];
        ushort4 o;
        o.x = f2bf(v.x); o.y = f2bf(v.y); o.z = f2bf(v.z); o.w = f2bf(v.w);
        reinterpret_cast<ushort4*>(dst)[off] = o;
    }
}

// ---------------------------------------------------------------------------
// 2-phase counted-vmcnt GEMM (T3 minimum recipe, m230-V0 structure):
// C = A[M x 1024] @ W[N x 1024]^T. 128x128 tile, BK=64, 256 thr (4 waves 2x2),
// TRUE double buffer (64 KB LDS -> 2 blocks/CU). Per K-tile:
//   STAGE(t+1, buf^1); ds_read 16x b128 (cur); lgkmcnt(0)+sched_barrier;
//   setprio(1) 32 MFMA setprio(0); vmcnt(0); s_barrier.
// Raw s_barrier only. XOR-swizzled LDS (pre-swizzled global source).
// XCD-chunked bijective block swizzle, n-fastest (A-panel L2 locality).
// SPLIT: cols [0,1024)->O0 [1024,2048)->O1 [2048,3072)->O2 bf16; else f32 O0.
// ---------------------------------------------------------------------------
template <bool C_F32, bool SPLIT>
__global__ __launch_bounds__(256, 2) void gemm2ph_kernel(
    const unsigned short* __restrict__ Ab,
    const unsigned short* __restrict__ Wb,
    int NB,
    void* __restrict__ O0, void* __restrict__ O1, void* __restrict__ O2)
{
    __shared__ __align__(16) unsigned short As[2][8192];   // 2 x 128x64, 32 KB
    __shared__ __align__(16) unsigned short Bs[2][8192];   // 2 x 128x64, 32 KB

    const int tid  = threadIdx.x;
    const int lane = tid & 63;
    const int wave = tid >> 6;
    const int wm   = wave >> 1;
    const int wn   = wave & 1;
    const int lr   = lane & 15;
    const int lq   = lane >> 4;

    // XCD-chunked swizzle (grid % 8 == 0): XCD x owns a contiguous work chunk.
    const int cpx = gridDim.x >> 3;
    const int fid = blockIdx.x;
    const int swz = (fid & 7) * cpx + (fid >> 3);
    const int nb  = swz % NB;
    const int mb  = swz / NB;          // n-fastest: same-XCD neighbors share A
    const int m0  = mb * 128;
    const int n0  = nb * 128;

    const int srw = lane >> 3;         // 0..7
    const int sc8 = lane & 7;

    auto STAGE = [&](int t, int buf) {
        const int k0 = t * 64;
        #pragma unroll
        for (int u = 0; u < 4; ++u) {
            int r = u * 32 + wave * 8 + srw;
            int c = sc8 ^ (r & 7);     // pre-swizzled global source chunk
            gload(&Ab[(size_t)(m0 + r) * 1024 + k0 + c * 8],
                  &As[buf][u * 2048 + wave * 512]);
            gload(&Wb[(size_t)(n0 + r) * 1024 + k0 + c * 8],
                  &Bs[buf][u * 2048 + wave * 512]);
        }
    };

    f32x4 acc[4][4];
    #pragma unroll
    for (int i = 0; i < 4; ++i)
        #pragma unroll
        for (int j = 0; j < 4; ++j)
            acc[i][j] = (f32x4){0.f, 0.f, 0.f, 0.f};

    STAGE(0, 0);
    asm volatile("s_waitcnt vmcnt(0)" ::: "memory");
    __builtin_amdgcn_s_barrier();

    int buf = 0;
    for (int t = 0; t < 16; ++t) {
        if (t + 1 < 16) STAGE(t + 1, buf ^ 1);   // issue next-tile loads first

        bf16x8 af[2][4], bfr[2][4];
        #pragma unroll
        for (int ks = 0; ks < 2; ++ks) {
            #pragma unroll
            for (int i = 0; i < 4; ++i) {
                int row = wm * 64 + i * 16 + lr;
                af[ks][i] = *reinterpret_cast<const bf16x8*>(
                    &As[buf][row * 64 + (((ks * 4 + lq) ^ (row & 7)) << 3)]);
            }
            #pragma unroll
            for (int j = 0; j < 4; ++j) {
                int row = wn * 64 + j * 16 + lr;
                bfr[ks][j] = *reinterpret_cast<const bf16x8*>(
                    &Bs[buf][row * 64 + (((ks * 4 + lq) ^ (row & 7)) << 3)]);
            }
        }
        asm volatile("s_waitcnt lgkmcnt(0)" ::: "memory");
        __builtin_amdgcn_sched_barrier(0);
        __builtin_amdgcn_s_setprio(1);
        #pragma unroll
        for (int ks = 0; ks < 2; ++ks)
            #pragma unroll
            for (int i = 0; i < 4; ++i)
                #pragma unroll
                for (int j = 0; j < 4; ++j)
                    acc[i][j] = __builtin_amdgcn_mfma_f32_16x16x32_bf16(
                        af[ks][i], bfr[ks][j], acc[i][j], 0, 0, 0);
        __builtin_amdgcn_s_setprio(0);
        if (t + 1 < 16) asm volatile("s_waitcnt vmcnt(0)" ::: "memory");
        __builtin_amdgcn_s_barrier();
        buf ^= 1;
    }

    if (SPLIT) {
        const int tsel = n0 >> 10;               // uniform per block
        const int d0   = n0 & 1023;
        unsigned short* Out =
            (unsigned short*)(tsel == 0 ? O0 : tsel == 1 ? O1 : O2);
        #pragma unroll
        for (int i = 0; i < 4; ++i)
            #pragma unroll
            for (int j = 0; j < 4; ++j) {
                int col = d0 + wn * 64 + j * 16 + lr;
                #pragma unroll
                for (int r = 0; r < 4; ++r) {
                    int row = m0 + wm * 64 + i * 16 + lq * 4 + r;
                    Out[(size_t)row * 1024 + col] = f2bf(acc[i][j][r]);
                }
            }
    } else {
        float* Co = (float*)O0;
        #pragma unroll
        for (int i = 0; i < 4; ++i)
            #pragma unroll
            for (int j = 0; j < 4; ++j) {
                int col = n0 + wn * 64 + j * 16 + lr;
                #pragma unroll
                for (int r = 0; r < 4; ++r) {
                    int row = m0 + wm * 64 + i * 16 + lq * 4 + r;
                    Co[(size_t)row * 1024 + col] = acc[i][j][r];
                }
            }
    }
}

// ---------------------------------------------------------------------------
// Fallback GEMM (round-5 structure): C = A @ W^T, fp32 W staged via VGPRs.
// ---------------------------------------------------------------------------
#define GBM 128
#define GBN 128
#define GBK 64

template <bool A_F32, bool C_F32>
__global__ __launch_bounds__(256) void gemm_bt_kernel(
    const void* __restrict__ Av,
    const float* __restrict__ W,
    void* __restrict__ Cv,
    int M, int N, int K)
{
    __shared__ unsigned short As[GBM][GBK];
    __shared__ unsigned short Ws[GBN][GBK];

    const int tid  = threadIdx.x;
    const int lane = tid & 63;
    const int wave = tid >> 6;
    const int wm   = wave >> 1;
    const int wn   = wave & 1;
    const int lr   = lane & 15;
    const int lq   = lane >> 4;
    const int m0   = blockIdx.y * GBM;
    const int n0   = blockIdx.x * GBN;

    f32x4 acc[4][4];
    #pragma unroll
    for (int i = 0; i < 4; ++i)
        #pragma unroll
        for (int j = 0; j < 4; ++j)
            acc[i][j] = (f32x4){0.f, 0.f, 0.f, 0.f};

    for (int k0 = 0; k0 < K; k0 += GBK) {
        if (A_F32) {
            const float* A = (const float*)Av;
            #pragma unroll
            for (int i = 0; i < 8; ++i) {
                int idx = tid + i * 256;
                int row = idx >> 4;
                int c4  = idx & 15;
                float4 a = *reinterpret_cast<const float4*>(
                    &A[(size_t)(m0 + row) * K + k0 + c4 * 4]);
                ushort4 o;
                o.x = f2bf(a.x); o.y = f2bf(a.y);
                o.z = f2bf(a.z); o.w = f2bf(a.w);
                *reinterpret_cast<ushort4*>(&As[row][c4 * 4]) = o;
            }
        } else {
            const unsigned short* A = (const unsigned short*)Av;
            #pragma unroll
            for (int i = 0; i < 4; ++i) {
                int idx = tid + i * 256;
                int row = idx >> 3;
                int c8  = idx & 7;
                int4 v = *reinterpret_cast<const int4*>(
                    &A[(size_t)(m0 + row) * K + k0 + c8 * 8]);
                *reinterpret_cast<int4*>(&As[row][c8 * 8]) = v;
            }
        }
        #pragma unroll
        for (int i = 0; i < 8; ++i) {
            int idx = tid + i * 256;
            int row = idx >> 4;
            int c4  = idx & 15;
            float4 w = *reinterpret_cast<const float4*>(
                &W[(size_t)(n0 + row) * K + k0 + c4 * 4]);
            ushort4 o;
            o.x = f2bf(w.x); o.y = f2bf(w.y);
            o.z = f2bf(w.z); o.w = f2bf(w.w);
            *reinterpret_cast<ushort4*>(&Ws[row][c4 * 4]) = o;
        }
        __syncthreads();

        #pragma unroll
        for (int ks = 0; ks < 2; ++ks) {
            bf16x8 af[4], bfr[4];
            #pragma unroll
            for (int i = 0; i < 4; ++i)
                af[i] = *reinterpret_cast<const bf16x8*>(
                    &As[wm * 64 + i * 16 + lr][ks * 32 + lq * 8]);
            #pragma unroll
            for (int j = 0; j < 4; ++j)
                bfr[j] = *reinterpret_cast<const bf16x8*>(
                    &Ws[wn * 64 + j * 16 + lr][ks * 32 + lq * 8]);
            #pragma unroll
            for (int i = 0; i < 4; ++i)
                #pragma unroll
                for (int j = 0; j < 4; ++j)
                    acc[i][j] = __builtin_amdgcn_mfma_f32_16x16x32_bf16(
                        af[i], bfr[j], acc[i][j], 0, 0, 0);
        }
        __syncthreads();
    }

    #pragma unroll
    for (int i = 0; i < 4; ++i) {
        #pragma unroll
        for (int j = 0; j < 4; ++j) {
            int col = n0 + wn * 64 + j * 16 + lr;
            #pragma unroll
            for (int r = 0; r < 4; ++r) {
                int row = m0 + wm * 64 + i * 16 + lq * 4 + r;
                if (C_F32) {
                    ((float*)Cv)[(size_t)row * N + col] = acc[i][j][r];
                } else {
                    ((unsigned short*)Cv)[(size_t)row * N + col] = f2bf(acc[i][j][r]);
                }
            }
        }
    }
}

// ---------------------------------------------------------------------------
// Fixup: tail rows via W_ns. +unroll 4 so the shfl-reduce chains pipeline.
// ---------------------------------------------------------------------------
__global__ __launch_bounds__(512) void fixup_kernel(
    const float* __restrict__ x,
    const float* __restrict__ Wq_ns,
    const float* __restrict__ Wk_ns,
    const float* __restrict__ Wv_ns,
    unsigned short* __restrict__ Q,
    unsigned short* __restrict__ Kb,
    unsigned short* __restrict__ V)
{
    const int bid   = blockIdx.x;
    const int wgt   = bid >> 6;
    const int chunk = bid & 63;
    const int proj  = wgt >> 3;
    const int n     = wgt & 7;
    const float* Wns =
        (proj == 0 ? Wq_ns : proj == 1 ? Wk_ns : Wv_ns) + (size_t)n * Dsz * Dsz;
    unsigned short* Out = (proj == 0 ? Q : proj == 1 ? Kb : V);
    const int l    = LSsz + n;
    const int b    = threadIdx.x >> 6;
    const int lane = threadIdx.x & 63;

    const float* xrow = x + ((size_t)b * Lsz + l) * Dsz;
    float4 xr[4];
    #pragma unroll
    for (int i = 0; i < 4; ++i)
        xr[i] = *reinterpret_cast<const float4*>(&xrow[lane * 4 + i * 256]);

    #pragma unroll 4
    for (int er = 0; er < 16; ++er) {
        const int e = chunk * 16 + er;
        const float* wrow = Wns + (size_t)e * Dsz;
        float s = 0.f;
        #pragma unroll
        for (int i = 0; i < 4; ++i) {
            float4 wv = *reinterpret_cast<const float4*>(&wrow[lane * 4 + i * 256]);
            s += wv.x * xr[i].x + wv.y * xr[i].y
               + wv.z * xr[i].z + wv.w * xr[i].w;
        }
        #pragma unroll
        for (int off = 32; off > 0; off >>= 1) s += __shfl_xor(s, off, 64);
        if (lane == 0) Out[((size_t)b * Lsz + l) * Dsz + e] = f2bf(s);
    }
}

// ---------------------------------------------------------------------------
// MFMA flash attention v3 + defer-max (T13). Otherwise identical to the
// verified 105.5 us kernel.
// ---------------------------------------------------------------------------
__global__ __launch_bounds__(256, 4) void attn_mfma_kernel(
    const unsigned short* __restrict__ Q,
    const unsigned short* __restrict__ K,
    const unsigned short* __restrict__ V,
    unsigned short* __restrict__ O)
{
    __shared__ __align__(16) unsigned short Klds[2 * 4096];   // 64x64 dbuf, 16 KB
    __shared__ __align__(16) unsigned short Vtlds[4096];      // 64x64 transposed, 8 KB
    __shared__ __align__(16) unsigned short Plds[4][1024];    // per-wave P + O bounce, 8 KB

    const int tid  = threadIdx.x;
    const int lane = tid & 63;
    const int wave = tid >> 6;
    const int lr   = lane & 15;
    const int lq   = lane >> 4;

    const int id = blockIdx.x;
    const int qt = 15 - ((id >> 3) & 15);
    const int bh = ((id >> 7) << 3) | (id & 7);
    const int h  = bh & (Hh - 1);
    const int b  = bh >> 4;
    const int qw = qt * 64 + wave * 16;
    const int nkt = qt + 1;

    const size_t base = (size_t)b * Lsz * Dsz + (size_t)h * HDsz;

    bf16x8 qf[2];
    #pragma unroll
    for (int h2 = 0; h2 < 2; ++h2) {
        bf16x8 t = *reinterpret_cast<const bf16x8*>(
            &Q[base + (size_t)(qw + lr) * Dsz + h2 * 32 + lq * 8]);
        #pragma unroll
        for (int e = 0; e < 8; ++e) {
            float f = bf2f((unsigned short)t[e]) * 0.125f;
            t[e] = (short)f2bf(f);
        }
        qf[h2] = t;
    }

    f32x4 acc[4];
    #pragma unroll
    for (int jd = 0; jd < 4; ++jd) acc[jd] = (f32x4){0.f, 0.f, 0.f, 0.f};
    float m_i[4] = {-1e30f, -1e30f, -1e30f, -1e30f};
    float l_i[4] = {0.f, 0.f, 0.f, 0.f};

    const int krow0 = tid >> 3;
    const int kc8   = tid & 7;
    const int vd0   = (tid & 7) * 8;
    const int vk0   = (tid >> 3) * 2;

    unsigned short* Pw = &Plds[wave][0];
    int4 vq0, vq1;

    #pragma unroll
    for (int it = 0; it < 2; ++it) {
        int row  = it * 32 + krow0;
        int csrc = kc8 ^ (row & 7);
        const unsigned short* ga = &K[base + (size_t)row * Dsz + csrc * 8];
        __builtin_amdgcn_global_load_lds(GLB(ga),
            LDSP(&Klds[it * 2048 + wave * 512]), 16, 0, 0);
    }
    vq0 = *reinterpret_cast<const int4*>(&V[base + (size_t)(vk0 + 0) * Dsz + vd0]);
    vq1 = *reinterpret_cast<const int4*>(&V[base + (size_t)(vk0 + 1) * Dsz + vd0]);

    for (int kt = 0; kt < nkt; ++kt) {
        const int k0 = kt * 64;
        const int kb = (kt & 1) * 4096;

        __syncthreads();

        {
            union { int4 v; unsigned short u[8]; } a, c;
            a.v = vq0; c.v = vq1;
            const int kc  = vk0 >> 3;
            const int klo = vk0 & 7;
            #pragma unroll
            for (int d = 0; d < 8; ++d) {
                int dd  = vd0 + d;
                int idx = dd * 64 + (((kc ^ (dd & 7)) << 3) | klo);
                ushort2 p; p.x = a.u[d]; p.y = c.u[d];
                *reinterpret_cast<ushort2*>(&Vtlds[idx]) = p;
            }
        }
        __syncthreads();

        if (kt + 1 < nkt) {
            const int k0n = k0 + 64;
            #pragma unroll
            for (int it = 0; it < 2; ++it) {
                int row  = it * 32 + krow0;
                int csrc = kc8 ^ (row & 7);
                const unsigned short* ga =
                    &K[base + (size_t)(k0n + row) * Dsz + csrc * 8];
                __builtin_amdgcn_global_load_lds(GLB(ga),
                    LDSP(&Klds[(kb ^ 4096) + it * 2048 + wave * 512]), 16, 0, 0);
            }
            vq0 = *reinterpret_cast<const int4*>(
                &V[base + (size_t)(k0n + vk0 + 0) * Dsz + vd0]);
            vq1 = *reinterpret_cast<const int4*>(
                &V[base + (size_t)(k0n + vk0 + 1) * Dsz + vd0]);
        }

        f32x4 sv[4];
        #pragma unroll
        for (int jt = 0; jt < 4; ++jt) sv[jt] = (f32x4){0.f, 0.f, 0.f, 0.f};

        __builtin_amdgcn_s_setprio(1);
        #pragma unroll
        for (int h2 = 0; h2 < 2; ++h2) {
            const int cs = (((h2 << 2) | lq) ^ (lr & 7)) << 3;
            #pragma unroll
            for (int jt = 0; jt < 4; ++jt) {
                bf16x8 kf = *reinterpret_cast<const bf16x8*>(
                    &Klds[kb + (jt * 16 + lr) * 64 + cs]);
                sv[jt] = __builtin_amdgcn_mfma_f32_16x16x32_bf16(
                    qf[h2], kf, sv[jt], 0, 0, 0);
            }
        }
        __builtin_amdgcn_s_setprio(0);

        if (k0 + 63 > qw) {
            #pragma unroll
            for (int jt = 0; jt < 4; ++jt) {
                int kpos = k0 + jt * 16 + lr;
                #pragma unroll
                for (int r = 0; r < 4; ++r) {
                    int q = qw + lq * 4 + r;
                    if (kpos > q) sv[jt][r] = -1e30f;
                }
            }
        }

        // ---- online softmax with defer-max (T13) ----
        float tm[4];
        #pragma unroll
        for (int r = 0; r < 4; ++r)
            tm[r] = fmaxf(fmaxf(sv[0][r], sv[1][r]), fmaxf(sv[2][r], sv[3][r]));
        #pragma unroll
        for (int off = 1; off < 16; off <<= 1)
            #pragma unroll
            for (int r = 0; r < 4; ++r)
                tm[r] = fmaxf(tm[r], __shfl_xor(tm[r], off, 64));

        float dm = fmaxf(fmaxf(tm[0] - m_i[0], tm[1] - m_i[1]),
                         fmaxf(tm[2] - m_i[2], tm[3] - m_i[3]));
        if (!__all(dm <= 8.0f)) {
            #pragma unroll
            for (int r = 0; r < 4; ++r) {
                float nm = fmaxf(m_i[r], tm[r]);
                float al = __expf(m_i[r] - nm);
                m_i[r] = nm;
                l_i[r] *= al;
                #pragma unroll
                for (int jd = 0; jd < 4; ++jd)
                    acc[jd][r] *= al;
            }
        }

        float rs[4];
        #pragma unroll
        for (int jt = 0; jt < 4; ++jt)
            #pragma unroll
            for (int r = 0; r < 4; ++r)
                sv[jt][r] = __expf(sv[jt][r] - m_i[r]);
        #pragma unroll
        for (int r = 0; r < 4; ++r)
            rs[r] = (sv[0][r] + sv[1][r]) + (sv[2][r] + sv[3][r]);
        #pragma unroll
        for (int off = 1; off < 16; off <<= 1)
            #pragma unroll
            for (int r = 0; r < 4; ++r)
                rs[r] += __shfl_xor(rs[r], off, 64);
        #pragma unroll
        for (int r = 0; r < 4; ++r) l_i[r] += rs[r];

        #pragma unroll
        for (int jt = 0; jt < 4; ++jt) {
            int kcol  = jt * 16 + lr;
            int chunk = kcol >> 3;
            int elem  = kcol & 7;
            #pragma unroll
            for (int r = 0; r < 4; ++r) {
                int qrow = lq * 4 + r;
                Pw[qrow * 64 + (((chunk ^ (qrow & 7)) << 3) | elem)] =
                    f2bf(sv[jt][r]);
            }
        }

        __builtin_amdgcn_s_setprio(1);
        #pragma unroll
        for (int h2 = 0; h2 < 2; ++h2) {
            const int cs = (((h2 << 2) | lq) ^ (lr & 7)) << 3;
            bf16x8 pf = *reinterpret_cast<const bf16x8*>(&Pw[lr * 64 + cs]);
            #pragma unroll
            for (int jd = 0; jd < 4; ++jd) {
                bf16x8 vf = *reinterpret_cast<const bf16x8*>(
                    &Vtlds[(jd * 16 + lr) * 64 + cs]);
                acc[jd] = __builtin_amdgcn_mfma_f32_16x16x32_bf16(
                    pf, vf, acc[jd], 0, 0, 0);
            }
        }
        __builtin_amdgcn_s_setprio(0);
    }

    float inv[4];
    #pragma unroll
    for (int r = 0; r < 4; ++r) inv[r] = 1.0f / l_i[r];
    #pragma unroll
    for (int jd = 0; jd < 4; ++jd) {
        #pragma unroll
        for (int r = 0; r < 4; ++r) {
            int qrow  = lq * 4 + r;
            int col   = jd * 16 + lr;
            int chunk = col >> 3;
            int elem  = col & 7;
            Pw[qrow * 64 + (((chunk ^ (qrow & 7)) << 3) | elem)] =
                f2bf(acc[jd][r] * inv[r]);
        }
    }
    #pragma unroll
    for (int it2 = 0; it2 < 2; ++it2) {
        int row = it2 * 8 + (lane >> 3);
        int c   = lane & 7;
        const int4 ov = *reinterpret_cast<const int4*>(
            &Pw[row * 64 + ((c ^ (row & 7)) << 3)]);
        *reinterpret_cast<int4*>(&O[base + (size_t)(qw + row) * Dsz + c * 8]) = ov;
    }
}

// ---------------------------------------------------------------------------
extern "C" void kernel_launch(void* const* d_in, const int* in_sizes, int n_in,
                              void* d_out, int out_size, void* d_ws, size_t ws_size,
                              hipStream_t stream)
{
    const float* x     = (const float*)d_in[0];
    const float* Wq_s  = (const float*)d_in[2];
    const float* Wk_s  = (const float*)d_in[3];
    const float* Wv_s  = (const float*)d_in[4];
    const float* Wq_ns = (const float*)d_in[5];
    const float* Wk_ns = (const float*)d_in[6];
    const float* Wv_ns = (const float*)d_in[7];
    const float* W_out = (const float*)d_in[8];
    float* out = (float*)d_out;

    const size_t nElem = (size_t)Bsz * Lsz * Dsz;            // 8388608
    unsigned short* Q    = (unsigned short*)d_ws;
    unsigned short* Kb   = Q + nElem;
    unsigned short* V    = Kb + nElem;
    unsigned short* Xb   = V + nElem;                        // xb, later O
    unsigned short* Wcat = Xb + nElem;
    unsigned short* Wob  = Wcat + 3 * 1048576;
    const size_t need = (4 * nElem + 4 * 1048576) * sizeof(unsigned short);

    if (ws_size >= need) {
        // ---- fast path: bf16 cast once, 2-phase counted-vmcnt GEMMs ----
        cast_kernel<<<3072, 256, 0, stream>>>(x, Wq_s, Wk_s, Wv_s, W_out,
                                              Xb, Wcat, Wob);
        // QKV: M=8192, N=3072 -> 64 m-blocks x 24 n-blocks = 1536 (%8==0)
        gemm2ph_kernel<false, true><<<1536, 256, 0, stream>>>(
            Xb, Wcat, 24, Q, Kb, V);
        fixup_kernel<<<24 * 64, 512, 0, stream>>>(x, Wq_ns, Wk_ns, Wv_ns, Q, Kb, V);
        unsigned short* O = Xb;   // xb dead after qkv gemm; reuse for attn out
        attn_mfma_kernel<<<Bsz * Hh * (Lsz / 64), 256, 0, stream>>>(Q, Kb, V, O);
        // out proj: M=8192, N=1024 -> 64 x 8 = 512 blocks (%8==0)
        gemm2ph_kernel<true, false><<<512, 256, 0, stream>>>(
            O, Wob, 8, out, nullptr, nullptr);
    } else {
        // ---- fallback (round-5 path), needs only 4*nElem*2 bytes ----
        unsigned short* O = Xb;
        dim3 ggrid(Dsz / GBN, (Bsz * Lsz) / GBM);
        gemm_bt_kernel<true, false><<<ggrid, 256, 0, stream>>>(x, Wq_s, Q,  Bsz * Lsz, Dsz, Dsz);
        gemm_bt_kernel<true, false><<<ggrid, 256, 0, stream>>>(x, Wk_s, Kb, Bsz * Lsz, Dsz, Dsz);
        gemm_bt_kernel<true, false><<<ggrid, 256, 0, stream>>>(x, Wv_s, V,  Bsz * Lsz, Dsz, Dsz);
        fixup_kernel<<<24 * 64, 512, 0, stream>>>(x, Wq_ns, Wk_ns, Wv_ns, Q, Kb, V);
        attn_mfma_kernel<<<Bsz * Hh * (Lsz / 64), 256, 0, stream>>>(Q, Kb, V, O);
        gemm_bt_kernel<false, true><<<ggrid, 256, 0, stream>>>(O, W_out, out, Bsz * Lsz, Dsz, Dsz);
    }
}